// Round 5
// baseline (1014.893 us; speedup 1.0000x reference)
//
#include <hip/hip_runtime.h>
#include <cstddef>

static constexpr int N_NODES = 50000;
static constexpr int N_EDGES = 400000;
static constexpr int D = 256;
static constexpr int R = 2;
static constexpr int M_PAD = 50048;   // 391 * 128 (MFMA grid pad)
static constexpr int CAP = 32;        // bucket capacity; max seg degree ~20 (Poisson(4))
static constexpr int NSEG = N_NODES * R;

typedef _Float16 f16x8 __attribute__((ext_vector_type(8)));
typedef float f32x4 __attribute__((ext_vector_type(4)));

__device__ __forceinline__ unsigned short f2h(float f) {
    _Float16 h = (_Float16)f;
    return *(unsigned short*)&h;
}

#define GLOAD16(g, l)                                                          \
    __builtin_amdgcn_global_load_lds(                                          \
        (const __attribute__((address_space(1))) void*)(g),                    \
        (__attribute__((address_space(3))) void*)(l), 16, 0, 0)

// ===========================================================================
// fp32 multi-slab vector GEMM — VERIFIED in round 1. X-path must stay fp32:
// the MoE top-1 gate is discontinuous in X3; bf16 X-path noise flips argmax
// for ~50 near-tie nodes (round-2 failure). Do not lower precision here
// without split-precision accumulation (>= 2^-22 rel).
// ===========================================================================
struct GemmArgs {
    const float* xs[4];
    const float* ws[4];
    int ks[4];
    int strides[4];
    int nslab;
    int M;
    const float* bias;
    float* out;
};

template<int ACT>
__global__ __launch_bounds__(256)
void gemm_f32(GemmArgs a) {
    __shared__ float As[16][68];
    __shared__ float Bs[16][64];
    const int tid  = threadIdx.x;
    const int row0 = blockIdx.x * 64;
    const int n0   = blockIdx.y * 64;
    const int tx   = tid & 15, ty = tid >> 4;
    const int arow = tid >> 2;
    const int aq   = (tid & 3) << 2;
    const int brow = tid >> 4;
    const int bcol = (tid & 15) << 2;

    float acc[4][4] = {};

    for (int s = 0; s < a.nslab; ++s) {
        const float* __restrict__ xp = a.xs[s];
        const float* __restrict__ wp = a.ws[s];
        const int K = a.ks[s];
        const int stride = a.strides[s];
        for (int k0 = 0; k0 < K; k0 += 16) {
            float4 av = make_float4(0.f, 0.f, 0.f, 0.f);
            const int grow = row0 + arow;
            if (grow < a.M)
                av = *(const float4*)(xp + (size_t)grow * stride + (k0 + aq));
            const float4 bv = *(const float4*)(wp + (size_t)(k0 + brow) * D + (n0 + bcol));
            __syncthreads();
            As[aq + 0][arow] = av.x;
            As[aq + 1][arow] = av.y;
            As[aq + 2][arow] = av.z;
            As[aq + 3][arow] = av.w;
            *(float4*)&Bs[brow][bcol] = bv;
            __syncthreads();
            #pragma unroll
            for (int kk = 0; kk < 16; ++kk) {
                const float4 af = *(const float4*)&As[kk][ty << 2];
                const float4 bf = *(const float4*)&Bs[kk][tx << 2];
                const float aa[4] = {af.x, af.y, af.z, af.w};
                const float bb[4] = {bf.x, bf.y, bf.z, bf.w};
                #pragma unroll
                for (int i = 0; i < 4; ++i)
                    #pragma unroll
                    for (int j = 0; j < 4; ++j)
                        acc[i][j] = fmaf(aa[i], bb[j], acc[i][j]);
            }
        }
    }

    #pragma unroll
    for (int i = 0; i < 4; ++i) {
        const int grow = row0 + (ty << 2) + i;
        if (grow >= a.M) continue;
        float4 o;
        float* op = (float*)&o;
        #pragma unroll
        for (int j = 0; j < 4; ++j) {
            const int col = n0 + (tx << 2) + j;
            float v = acc[i][j] + a.bias[col];
            if (ACT == 1) {
                const float scale = 1.0507009873554804934f;
                const float alpha = 1.6732632423543772848f;
                v = (v > 0.f) ? scale * v : scale * alpha * (expf(v) - 1.f);
            }
            op[j] = v;
        }
        *(float4*)(a.out + (size_t)grow * D + n0 + (tx << 2)) = o;
    }
}

// ===========================================================================
// f16 MFMA GEMM (MoE only this round — continuous error path).
// 128x128 tile, BK=64, 4 waves, 4x4 frags of mfma_f32_16x16x32_f16.
// LDS XOR granule swizzle (T2, rule #21): global source pre-swizzled so the
// linear global_load_lds dest + XOR'd ds_read_b128 are a consistent involution.
// ===========================================================================
struct MSlab { const unsigned short* x; const unsigned short* w; int xstr, wstr, klen; };
struct MArgs {
    MSlab sl[4];
    int nslab, M;
    const float* bias;
    const int* sel;
    int expert;
    void* out;
    int ldc;
};

template<int ACT, bool MASK, bool SELB, bool OUTF16>
__global__ __launch_bounds__(256)
void mgemm(MArgs a) {
    __shared__ unsigned short As[128 * 64];
    __shared__ unsigned short Bs[128 * 64];
    const int tid  = threadIdx.x;
    const int wave = tid >> 6, lane = tid & 63;
    const int wm = wave >> 1, wn = wave & 1;
    const int row0 = blockIdx.x * 128;
    const int n0   = blockIdx.y * 128;

    const int srow = lane >> 3;                               // 0..7
    const int scol = ((lane & 7) ^ (lane >> 3)) << 3;         // swizzled src granule

    f32x4 acc[4][4] = {};

    for (int s = 0; s < a.nslab; ++s) {
        const unsigned short* xp = a.sl[s].x;
        const unsigned short* wp = a.sl[s].w;
        const int xstr = a.sl[s].xstr, wstr = a.sl[s].wstr, klen = a.sl[s].klen;
        for (int k0 = 0; k0 < klen; k0 += 64) {
            __syncthreads();
            #pragma unroll
            for (int i = 0; i < 4; ++i) {
                const int r = wave * 32 + i * 8;
                GLOAD16(xp + (size_t)(row0 + r + srow) * xstr + k0 + scol, &As[r * 64]);
            }
            #pragma unroll
            for (int i = 0; i < 4; ++i) {
                const int r = wave * 32 + i * 8;
                GLOAD16(wp + (size_t)(n0 + r + srow) * wstr + k0 + scol, &Bs[r * 64]);
            }
            __syncthreads();

            #pragma unroll
            for (int kk = 0; kk < 2; ++kk) {
                const int gk = kk * 4 + (lane >> 4);          // 16B k-granule 0..7
                f16x8 af[4], bfr[4];
                #pragma unroll
                for (int m = 0; m < 4; ++m) {
                    const int rr = wm * 64 + m * 16 + (lane & 15);
                    af[m] = *(const f16x8*)&As[rr * 64 + ((gk ^ (rr & 7)) << 3)];
                }
                #pragma unroll
                for (int n = 0; n < 4; ++n) {
                    const int rr = wn * 64 + n * 16 + (lane & 15);
                    bfr[n] = *(const f16x8*)&Bs[rr * 64 + ((gk ^ (rr & 7)) << 3)];
                }
                #pragma unroll
                for (int m = 0; m < 4; ++m)
                    #pragma unroll
                    for (int n = 0; n < 4; ++n)
                        acc[m][n] = __builtin_amdgcn_mfma_f32_16x16x32_f16(
                            af[m], bfr[n], acc[m][n], 0, 0, 0);
            }
        }
    }

    // C/D: col = lane&15, row = (lane>>4)*4 + reg   [m89-verified layout]
    const int erow = (lane >> 4) * 4;
    const int ecol = lane & 15;
    #pragma unroll
    for (int m = 0; m < 4; ++m) {
        #pragma unroll
        for (int r = 0; r < 4; ++r) {
            const int grow = row0 + wm * 64 + m * 16 + erow + r;
            if (grow >= a.M) continue;
            int sv = 0;
            if (MASK || SELB) sv = a.sel[grow];
            #pragma unroll
            for (int n = 0; n < 4; ++n) {
                const int gcol = n0 + wn * 64 + n * 16 + ecol;
                const float b = SELB ? a.bias[sv * 256 + gcol] : a.bias[gcol];
                float v = acc[m][n][r] + b;
                if (ACT == 2) v = (v >= 0.f) ? v : 0.01f * v;
                if (MASK && sv != a.expert) v = 0.f;
                if (OUTF16)
                    ((unsigned short*)a.out)[(size_t)grow * a.ldc + gcol] = f2h(v);
                else
                    ((float*)a.out)[(size_t)grow * a.ldc + gcol] = v;
            }
        }
    }
}

// ===========================================================================
// bucket-CSR build (once; edges identical for both RGCN layers)
// ===========================================================================
__global__ __launch_bounds__(256)
void csr_build(const int* __restrict__ ei, const int* __restrict__ et,
               int* cnt, int* slots) {
    const int e = blockIdx.x * 256 + threadIdx.x;
    if (e >= N_EDGES) return;
    const int src = ei[e];
    const int dst = ei[N_EDGES + e];
    const int seg = dst * R + et[e];
    const int slot = atomicAdd(&cnt[seg], 1);
    if (slot < CAP) slots[(size_t)seg * CAP + slot] = src;
}

// one wave per segment: mean of gathered X rows -> Ab[(n-local)*512 + r*256 + d]
__global__ __launch_bounds__(256)
void aggregate(const float* __restrict__ X, const int* __restrict__ cnt,
               const int* __restrict__ slots, float* __restrict__ Ab,
               int seg0, int nseg) {
    const int w = blockIdx.x * 4 + (threadIdx.x >> 6);
    if (w >= nseg) return;
    const int lane = threadIdx.x & 63;
    const int s = seg0 + w;
    const int m = min(cnt[s], CAP);
    const int* sl = slots + (size_t)s * CAP;
    float4 acc = make_float4(0.f, 0.f, 0.f, 0.f);
    for (int i = 0; i < m; ++i) {
        const float4 v = *(const float4*)(X + (size_t)sl[i] * 256 + lane * 4);
        acc.x += v.x; acc.y += v.y; acc.z += v.z; acc.w += v.w;
    }
    const float inv = (m > 0) ? 1.0f / (float)m : 0.0f;
    acc.x *= inv; acc.y *= inv; acc.z *= inv; acc.w *= inv;
    *(float4*)(Ab + (size_t)(w >> 1) * 512 + (w & 1) * 256 + lane * 4) = acc;
}

// gate: sel[n] = argmax(X3_f32[n] @ w_gate)  (NE=2, tie -> 0) — round-1 verified
__global__ __launch_bounds__(256)
void gate_kernel(const float* __restrict__ x, const float* __restrict__ wg,
                 int* sel, int M) {
    __shared__ float wl[2 * D];
    const int tid = threadIdx.x;
    wl[tid] = wg[tid];
    wl[tid + 256] = wg[tid + 256];
    __syncthreads();
    const int wave = tid >> 6, lane = tid & 63;
    const int row = blockIdx.x * 4 + wave;
    if (row >= M) return;
    const float* xr = x + (size_t)row * D;
    float z0 = 0.f, z1 = 0.f;
    #pragma unroll
    for (int p = 0; p < 4; ++p) {
        const int k = lane + (p << 6);
        const float xv = xr[k];
        z0 = fmaf(xv, wl[2 * k], z0);
        z1 = fmaf(xv, wl[2 * k + 1], z1);
    }
    #pragma unroll
    for (int off = 32; off; off >>= 1) {
        z0 += __shfl_down(z0, off, 64);
        z1 += __shfl_down(z1, off, 64);
    }
    if (lane == 0) sel[row] = (z1 > z0) ? 1 : 0;
}

// MoE weight transpose+f16: dst[n*stride + koff + k] = f16(src[k*256 + n])
struct WJob4 { const float* src[4]; unsigned short* dst[4]; int stride[4]; };
__global__ __launch_bounds__(256)
void wconv_moe(WJob4 j) {
    const int job = blockIdx.y;
    const int i = blockIdx.x * 256 + threadIdx.x;   // 256*256
    const int k = i >> 8, n = i & 255;
    j.dst[job][(size_t)n * j.stride[job] + k] = f2h(j.src[job][i]);
}

// X3 f32 -> f16 (covers M_PAD rows; pad rows hold poison -> tiny denormal -> -0)
__global__ __launch_bounds__(256)
void x3conv(const float* __restrict__ X3, unsigned short* __restrict__ X3h) {
    const int i = blockIdx.x * 256 + threadIdx.x;   // float4 units
    const float4 v = ((const float4*)X3)[i];
    ushort4 o = make_ushort4(f2h(v.x), f2h(v.y), f2h(v.z), f2h(v.w));
    ((ushort4*)X3h)[i] = o;
}

// ===========================================================================
extern "C" void kernel_launch(void* const* d_in, const int* in_sizes, int n_in,
                              void* d_out, int out_size, void* d_ws, size_t ws_size,
                              hipStream_t stream) {
    const float* des    = (const float*)d_in[0];
    const float* twt    = (const float*)d_in[1];
    const float* nump   = (const float*)d_in[2];
    const float* catp   = (const float*)d_in[3];
    const int*   ei     = (const int*)d_in[4];
    const int*   et     = (const int*)d_in[5];
    const float* W_in   = (const float*)d_in[6];
    const float* b_in   = (const float*)d_in[7];
    const float* W_rel  = (const float*)d_in[8];
    const float* W_root = (const float*)d_in[9];
    const float* b_rg   = (const float*)d_in[10];
    const float* w_gate = (const float*)d_in[11];
    const float* We1    = (const float*)d_in[12];
    const float* be1    = (const float*)d_in[13];
    const float* We2    = (const float*)d_in[14];
    const float* be2    = (const float*)d_in[15];

    // ---- workspace layout (~193 MB) ----
    char* ws = (char*)d_ws;
    size_t off = 0;
    float* X1 = (float*)(ws + off); off += (size_t)M_PAD * 256 * 4;   // 51.25 MB (X3 aliases)
    float* X3 = X1;
    float* X2 = (float*)(ws + off); off += (size_t)M_PAD * 256 * 4;   // 51.25 MB
    // regionA: Ab (layers) then {X3h | H} (MoE) — disjoint lifetimes
    char* regionA = ws + off; off += (size_t)M_PAD * 512 * 2 + (size_t)M_PAD * 256 * 2; // 76.9 MB
    float* Ab = (float*)regionA;                                       // 25024*512*4 = 51.25 MB used
    unsigned short* X3h = (unsigned short*)regionA;                    // M_PAD*256*2 = 25.62 MB
    unsigned short* H   = (unsigned short*)(regionA + (size_t)M_PAD * 256 * 2); // M_PAD*512*2
    int* cnt   = (int*)(ws + off); off += (size_t)NSEG * 4;
    int* sel   = (int*)(ws + off); off += (size_t)N_NODES * 4;
    int* slots = (int*)(ws + off); off += (size_t)NSEG * CAP * 4;      // 12.8 MB
    unsigned short* Wt_e1h0 = (unsigned short*)(ws + off); off += 256 * 256 * 2;
    unsigned short* Wt_e1h1 = (unsigned short*)(ws + off); off += 256 * 256 * 2;
    unsigned short* Wt_e2h  = (unsigned short*)(ws + off); off += 256 * 512 * 2;

    const dim3 blk(256);

    // ---- CSR build (once) + MoE weight conv ----
    hipMemsetAsync(cnt, 0, (size_t)NSEG * 4, stream);
    csr_build<<<(N_EDGES + 255) / 256, blk, 0, stream>>>(ei, et, cnt, slots);
    {
        WJob4 j;
        j.src[0] = We1;           j.dst[0] = Wt_e1h0;      j.stride[0] = 256;
        j.src[1] = We1 + D * D;   j.dst[1] = Wt_e1h1;      j.stride[1] = 256;
        j.src[2] = We2;           j.dst[2] = Wt_e2h;       j.stride[2] = 512;
        j.src[3] = We2 + D * D;   j.dst[3] = Wt_e2h + 256; j.stride[3] = 512;
        wconv_moe<<<dim3(256, 4), blk, 0, stream>>>(j);
    }

    // ---- stage 1: X1 = selu(concat @ W_in + b_in)  [fp32, full M] ----
    {
        GemmArgs g{};
        g.xs[0] = des;  g.ws[0] = W_in;            g.ks[0] = 128; g.strides[0] = 128;
        g.xs[1] = twt;  g.ws[1] = W_in + 128 * D;  g.ks[1] = 64;  g.strides[1] = 64;
        g.xs[2] = nump; g.ws[2] = W_in + 192 * D;  g.ks[2] = 32;  g.strides[2] = 32;
        g.xs[3] = catp; g.ws[3] = W_in + 224 * D;  g.ks[3] = 32;  g.strides[3] = 32;
        g.nslab = 4; g.M = N_NODES; g.bias = b_in; g.out = X1;
        hipLaunchKernelGGL((gemm_f32<1>), dim3(782, 4), blk, 0, stream, g);
    }

    // ---- RGCN layers, 2 node-chunks each (Ab reused; CSR reused) ----
    const float* rg_in[2]  = {X1, X2};
    float*       rg_out[2] = {X2, X3};
    const int c0s[2] = {0, 25000};
    const int c1s[2] = {25000, 50000};
    for (int layer = 0; layer < 2; ++layer) {
        for (int c = 0; c < 2; ++c) {
            const int c0 = c0s[c], c1 = c1s[c];
            const int mrows = c1 - c0;
            const int nseg = mrows * R;
            aggregate<<<(nseg + 3) / 4, blk, 0, stream>>>(
                rg_in[layer], cnt, slots, Ab, c0 * R, nseg);
            GemmArgs g{};
            g.xs[0] = rg_in[layer] + (size_t)c0 * 256; g.ws[0] = W_root;      g.ks[0] = D; g.strides[0] = D;
            g.xs[1] = Ab;                              g.ws[1] = W_rel;       g.ks[1] = D; g.strides[1] = 512;
            g.xs[2] = Ab + 256;                        g.ws[2] = W_rel + D*D; g.ks[2] = D; g.strides[2] = 512;
            g.nslab = 3; g.M = mrows; g.bias = b_rg;
            g.out = rg_out[layer] + (size_t)c0 * 256;
            hipLaunchKernelGGL((gemm_f32<0>), dim3((mrows + 63) / 64, 4), blk, 0, stream, g);
        }
    }

    // ---- MoE top-1 ----
    gate_kernel<<<(N_NODES + 3) / 4, blk, 0, stream>>>(X3, w_gate, sel, N_NODES);
    x3conv<<<M_PAD / 4, blk, 0, stream>>>(X3, X3h);

    for (int e = 0; e < 2; ++e) {
        MArgs g{};
        g.sl[0] = {X3h, (e == 0) ? Wt_e1h0 : Wt_e1h1, 256, 256, 256};
        g.nslab = 1; g.M = N_NODES;
        g.bias = be1 + e * 256; g.sel = sel; g.expert = e;
        g.out = H + e * 256; g.ldc = 512;
        hipLaunchKernelGGL((mgemm<2, true, false, true>), dim3(M_PAD / 128, 2), blk, 0, stream, g);
    }
    {
        MArgs g{};
        g.sl[0] = {H, Wt_e2h, 512, 512, 512};
        g.nslab = 1; g.M = N_NODES;
        g.bias = be2; g.sel = sel;
        g.out = d_out; g.ldc = 256;
        hipLaunchKernelGGL((mgemm<0, false, true, false>), dim3(M_PAD / 128, 2), blk, 0, stream, g);
    }
}

// Round 6
// 709.033 us; speedup vs baseline: 1.4314x; 1.4314x over previous
//
#include <hip/hip_runtime.h>
#include <cstddef>

static constexpr int N_NODES = 50000;
static constexpr int N_EDGES = 400000;
static constexpr int D = 256;
static constexpr int R = 2;
static constexpr int M_PAD = 50048;   // 391 * 128 (MFMA grid pad)
static constexpr int CAP = 32;        // bucket capacity (max seg degree ~20, Poisson(4))
static constexpr int NSEG = N_NODES * R;
static constexpr int XROWS = 50048;   // fp32 X buffer rows
static constexpr int AB_ROWS = 25024; // per-chunk aggregate rows (+pad)

typedef _Float16 f16x8 __attribute__((ext_vector_type(8)));
typedef short bf16x8 __attribute__((ext_vector_type(8)));
typedef float f32x4 __attribute__((ext_vector_type(4)));

__device__ __forceinline__ unsigned short f2h(float f) {
    _Float16 h = (_Float16)f;
    return *(unsigned short*)&h;
}
__device__ __forceinline__ unsigned short f2bf(float f) {
    unsigned u = __float_as_uint(f);
    u += 0x7FFF + ((u >> 16) & 1);          // RNE
    return (unsigned short)(u >> 16);
}
__device__ __forceinline__ float bf2f(unsigned short h) {
    return __uint_as_float((unsigned)h << 16);
}

#define GLOAD16(g, l)                                                          \
    __builtin_amdgcn_global_load_lds(                                          \
        (const __attribute__((address_space(1))) void*)(g),                    \
        (__attribute__((address_space(3))) void*)(l), 16, 0, 0)

// ===========================================================================
// bf16x3 split-MFMA GEMM: fp32-grade accuracy on the matrix pipe.
// A: fp32 global, reg-staged, Dekker-split into 3 bf16 planes in LDS
//    (swizzled ds_write; slot = g ^ ((row>>1)&3) -> <=2-way bank conflicts).
// B: weights pre-split into 3 bf16 planes [n][Ktot]; global_load_lds with
//    source-granule permutation (R5-verified pattern).
// 6 MFMA products per frag pair: h1h1,h1h2,h2h1,h1h3,h3h1,h2h2 (err ~2^-25).
// Tile 128x128, BK=32, 4 waves, 4x4 frags of mfma_f32_16x16x32_bf16.
// ===========================================================================
struct SSlab { const float* x; int xstr; int kstart; int mload; };
struct SArgs {
    SSlab sl[4];
    int nslab;
    const unsigned short* wt;   // 3 planes, plane stride 256*Ktot
    int Ktot;
    int M;                      // real output rows
    const float* bias;
    void* out;                  // OUTMODE 0: float*, 1: f16 (ushort*)
};

template<int ACT, int OUTMODE>   // ACT: 0 none, 1 selu.  OUTMODE: 0 fp32, 1 f16
__global__ __launch_bounds__(256, 2)
void sgemm(SArgs a) {
    __shared__ unsigned short As[3][128 * 32];
    __shared__ unsigned short Bs[3][128 * 32];
    const int tid  = threadIdx.x;
    const int wave = tid >> 6, lane = tid & 63;
    const int wm = wave >> 1, wn = wave & 1;
    const int row0 = blockIdx.x * 128;
    const int n0   = blockIdx.y * 128;

    const int arow  = tid >> 1;          // A-staging row this thread owns
    const int ahalf = tid & 1;           // k-half (16 elems)
    const int br_   = tid >> 2;          // B-staging row within 64-row pass
    const int bg_   = tid & 3;           // B-staging LDS granule slot

    const int gk   = lane >> 4;          // frag k-granule 0..3
    const int frow = lane & 15;
    const int fslot = (gk ^ ((frow >> 1) & 3)) << 3;   // swizzled elem offset

    f32x4 acc[4][4] = {};

    for (int ks = 0; ks < a.Ktot; ks += 32) {
        int s = a.nslab - 1;
        while (s > 0 && ks < a.sl[s].kstart) --s;
        const float* xb = a.sl[s].x;
        const int xstr  = a.sl[s].xstr;
        const int kloc  = ks - a.sl[s].kstart;
        const int mload = a.sl[s].mload;

        // A: guarded fp32 register loads (global only; before barrier)
        float ev[16];
        {
            const int gr = row0 + arow;
            if (gr < mload) {
                const float* ap = xb + (size_t)gr * xstr + kloc + ahalf * 16;
                *(float4*)&ev[0]  = ((const float4*)ap)[0];
                *(float4*)&ev[4]  = ((const float4*)ap)[1];
                *(float4*)&ev[8]  = ((const float4*)ap)[2];
                *(float4*)&ev[12] = ((const float4*)ap)[3];
            } else {
                #pragma unroll
                for (int j = 0; j < 16; ++j) ev[j] = 0.f;
            }
        }

        __syncthreads();   // prev iteration's compute done

        // B: 3 planes x 2 passes via global_load_lds, permuted source granule
        #pragma unroll
        for (int p = 0; p < 3; ++p) {
            #pragma unroll
            for (int q = 0; q < 2; ++q) {
                const int r = q * 64 + br_;
                const int gsrc = (bg_ ^ ((r >> 1) & 3)) << 3;
                GLOAD16(a.wt + (size_t)p * 256 * a.Ktot + (size_t)(n0 + r) * a.Ktot + ks + gsrc,
                        &Bs[p][(q * 64 + wave * 16) * 32]);
            }
        }

        // A: Dekker bf16x3 split + swizzled ds_write (2 granules of 8 elems)
        {
            const int sswz = (arow >> 1) & 3;
            #pragma unroll
            for (int g = 0; g < 2; ++g) {
                union { bf16x8 v; unsigned short u[8]; } p1, p2, p3;
                #pragma unroll
                for (int j = 0; j < 8; ++j) {
                    const float v = ev[g * 8 + j];
                    const unsigned short h1 = f2bf(v);
                    const float r1 = v - bf2f(h1);        // exact
                    const unsigned short h2 = f2bf(r1);
                    const float r2 = r1 - bf2f(h2);       // exact
                    p1.u[j] = h1; p2.u[j] = h2; p3.u[j] = f2bf(r2);
                }
                const int slot = ((ahalf * 2 + g) ^ sswz) << 3;
                *(bf16x8*)&As[0][arow * 32 + slot] = p1.v;
                *(bf16x8*)&As[1][arow * 32 + slot] = p2.v;
                *(bf16x8*)&As[2][arow * 32 + slot] = p3.v;
            }
        }

        __syncthreads();   // staging (vmcnt+lgkm) drained

        bf16x8 bq[4][3];
        #pragma unroll
        for (int n = 0; n < 4; ++n) {
            const int rr = wn * 64 + n * 16 + frow;
            #pragma unroll
            for (int p = 0; p < 3; ++p)
                bq[n][p] = *(const bf16x8*)&Bs[p][rr * 32 + fslot];
        }
        #pragma unroll
        for (int m = 0; m < 4; ++m) {
            const int rr = wm * 64 + m * 16 + frow;
            const bf16x8 a1 = *(const bf16x8*)&As[0][rr * 32 + fslot];
            const bf16x8 a2 = *(const bf16x8*)&As[1][rr * 32 + fslot];
            const bf16x8 a3 = *(const bf16x8*)&As[2][rr * 32 + fslot];
            #pragma unroll
            for (int n = 0; n < 4; ++n) {
                acc[m][n] = __builtin_amdgcn_mfma_f32_16x16x32_bf16(a1, bq[n][0], acc[m][n], 0, 0, 0);
                acc[m][n] = __builtin_amdgcn_mfma_f32_16x16x32_bf16(a1, bq[n][1], acc[m][n], 0, 0, 0);
                acc[m][n] = __builtin_amdgcn_mfma_f32_16x16x32_bf16(a2, bq[n][0], acc[m][n], 0, 0, 0);
                acc[m][n] = __builtin_amdgcn_mfma_f32_16x16x32_bf16(a1, bq[n][2], acc[m][n], 0, 0, 0);
                acc[m][n] = __builtin_amdgcn_mfma_f32_16x16x32_bf16(a3, bq[n][0], acc[m][n], 0, 0, 0);
                acc[m][n] = __builtin_amdgcn_mfma_f32_16x16x32_bf16(a2, bq[n][1], acc[m][n], 0, 0, 0);
            }
        }
    }

    // epilogue: C/D col = lane&15, row = (lane>>4)*4 + reg  [verified]
    const int erow = (lane >> 4) * 4;
    const int ecol = lane & 15;
    #pragma unroll
    for (int m = 0; m < 4; ++m) {
        #pragma unroll
        for (int r = 0; r < 4; ++r) {
            const int grow = row0 + wm * 64 + m * 16 + erow + r;
            if (grow >= a.M) continue;
            #pragma unroll
            for (int n = 0; n < 4; ++n) {
                const int gcol = n0 + wn * 64 + n * 16 + ecol;
                float v = acc[m][n][r] + a.bias[gcol];
                if (ACT == 1) {
                    const float scale = 1.0507009873554804934f;
                    const float alpha = 1.6732632423543772848f;
                    v = (v > 0.f) ? scale * v : scale * alpha * (expf(v) - 1.f);
                }
                if (OUTMODE == 0)
                    ((float*)a.out)[(size_t)grow * 256 + gcol] = v;
                else
                    ((unsigned short*)a.out)[(size_t)grow * 256 + gcol] = f2h(v);
            }
        }
    }
}

// ===========================================================================
// f16 MFMA GEMM for MoE (R5-verified, unchanged).
// ===========================================================================
struct MSlab { const unsigned short* x; const unsigned short* w; int xstr, wstr, klen; };
struct MArgs {
    MSlab sl[4];
    int nslab, M;
    const float* bias;
    const int* sel;
    int expert;
    void* out;
    int ldc;
};

template<int ACT, bool MASK, bool SELB, bool OUTF16>
__global__ __launch_bounds__(256)
void mgemm(MArgs a) {
    __shared__ unsigned short As[128 * 64];
    __shared__ unsigned short Bs[128 * 64];
    const int tid  = threadIdx.x;
    const int wave = tid >> 6, lane = tid & 63;
    const int wm = wave >> 1, wn = wave & 1;
    const int row0 = blockIdx.x * 128;
    const int n0   = blockIdx.y * 128;

    const int srow = lane >> 3;
    const int scol = ((lane & 7) ^ (lane >> 3)) << 3;

    f32x4 acc[4][4] = {};

    for (int s = 0; s < a.nslab; ++s) {
        const unsigned short* xp = a.sl[s].x;
        const unsigned short* wp = a.sl[s].w;
        const int xstr = a.sl[s].xstr, wstr = a.sl[s].wstr, klen = a.sl[s].klen;
        for (int k0 = 0; k0 < klen; k0 += 64) {
            __syncthreads();
            #pragma unroll
            for (int i = 0; i < 4; ++i) {
                const int r = wave * 32 + i * 8;
                GLOAD16(xp + (size_t)(row0 + r + srow) * xstr + k0 + scol, &As[r * 64]);
            }
            #pragma unroll
            for (int i = 0; i < 4; ++i) {
                const int r = wave * 32 + i * 8;
                GLOAD16(wp + (size_t)(n0 + r + srow) * wstr + k0 + scol, &Bs[r * 64]);
            }
            __syncthreads();

            #pragma unroll
            for (int kk = 0; kk < 2; ++kk) {
                const int gkk = kk * 4 + (lane >> 4);
                f16x8 af[4], bfr[4];
                #pragma unroll
                for (int m = 0; m < 4; ++m) {
                    const int rr = wm * 64 + m * 16 + (lane & 15);
                    af[m] = *(const f16x8*)&As[rr * 64 + ((gkk ^ (rr & 7)) << 3)];
                }
                #pragma unroll
                for (int n = 0; n < 4; ++n) {
                    const int rr = wn * 64 + n * 16 + (lane & 15);
                    bfr[n] = *(const f16x8*)&Bs[rr * 64 + ((gkk ^ (rr & 7)) << 3)];
                }
                #pragma unroll
                for (int m = 0; m < 4; ++m)
                    #pragma unroll
                    for (int n = 0; n < 4; ++n)
                        acc[m][n] = __builtin_amdgcn_mfma_f32_16x16x32_f16(
                            af[m], bfr[n], acc[m][n], 0, 0, 0);
            }
        }
    }

    const int erow = (lane >> 4) * 4;
    const int ecol = lane & 15;
    #pragma unroll
    for (int m = 0; m < 4; ++m) {
        #pragma unroll
        for (int r = 0; r < 4; ++r) {
            const int grow = row0 + wm * 64 + m * 16 + erow + r;
            if (grow >= a.M) continue;
            int sv = 0;
            if (MASK || SELB) sv = a.sel[grow];
            #pragma unroll
            for (int n = 0; n < 4; ++n) {
                const int gcol = n0 + wn * 64 + n * 16 + ecol;
                const float b = SELB ? a.bias[sv * 256 + gcol] : a.bias[gcol];
                float v = acc[m][n][r] + b;
                if (ACT == 2) v = (v >= 0.f) ? v : 0.01f * v;
                if (MASK && sv != a.expert) v = 0.f;
                if (OUTF16)
                    ((unsigned short*)a.out)[(size_t)grow * a.ldc + gcol] = f2h(v);
                else
                    ((float*)a.out)[(size_t)grow * a.ldc + gcol] = v;
            }
        }
    }
}

// ===========================================================================
// bucket-CSR build (R5-verified)
// ===========================================================================
__global__ __launch_bounds__(256)
void csr_build(const int* __restrict__ ei, const int* __restrict__ et,
               int* cnt, int* slots) {
    const int e = blockIdx.x * 256 + threadIdx.x;
    if (e >= N_EDGES) return;
    const int src = ei[e];
    const int dst = ei[N_EDGES + e];
    const int seg = dst * R + et[e];
    const int slot = atomicAdd(&cnt[seg], 1);
    if (slot < CAP) slots[(size_t)seg * CAP + slot] = src;
}

// one wave per segment: mean of gathered X rows (fp32) — R5-verified
__global__ __launch_bounds__(256)
void aggregate(const float* __restrict__ X, const int* __restrict__ cnt,
               const int* __restrict__ slots, float* __restrict__ Ab,
               int seg0, int nseg) {
    const int w = blockIdx.x * 4 + (threadIdx.x >> 6);
    if (w >= nseg) return;
    const int lane = threadIdx.x & 63;
    const int s = seg0 + w;
    const int m = min(cnt[s], CAP);
    const int* sl = slots + (size_t)s * CAP;
    float4 acc = make_float4(0.f, 0.f, 0.f, 0.f);
    for (int i = 0; i < m; ++i) {
        const float4 v = *(const float4*)(X + (size_t)sl[i] * 256 + lane * 4);
        acc.x += v.x; acc.y += v.y; acc.z += v.z; acc.w += v.w;
    }
    const float inv = (m > 0) ? 1.0f / (float)m : 0.0f;
    acc.x *= inv; acc.y *= inv; acc.z *= inv; acc.w *= inv;
    *(float4*)(Ab + (size_t)(w >> 1) * 512 + (w & 1) * 256 + lane * 4) = acc;
}

// ===========================================================================
// gate fold: w2f[k*2+j] = (Wall @ w_gate)[k,j] for k<768; w2f[1536+j] = b.wg
// ===========================================================================
__global__ __launch_bounds__(256)
void foldw(const float* __restrict__ W_root, const float* __restrict__ W_rel,
           const float* __restrict__ b_rg, const float* __restrict__ wg,
           float* __restrict__ w2f) {
    const int idx = blockIdx.x * 256 + threadIdx.x;
    if (idx >= 1538) return;
    if (idx < 1536) {
        const int k = idx >> 1, j = idx & 1;
        const float* row = (k < 256) ? W_root + (size_t)k * 256
                         : (k < 512) ? W_rel + (size_t)(k - 256) * 256
                                     : W_rel + 65536 + (size_t)(k - 512) * 256;
        float s = 0.f;
        for (int d = 0; d < 256; ++d) s += row[d] * wg[d * 2 + j];
        w2f[idx] = s;
    } else {
        const int j = idx - 1536;
        float s = 0.f;
        for (int d = 0; d < 256; ++d) s += b_rg[d] * wg[d * 2 + j];
        w2f[idx] = s;
    }
}

// gate from folded weights (fp32; X2/Ab are fp32 — exact layer-3 logits)
__global__ __launch_bounds__(256)
void gate2(const float* __restrict__ X2, const float* __restrict__ Ab,
           const float* __restrict__ w2f, int* sel, int c0, int mrows) {
    __shared__ float wl[1538];
    for (int i = threadIdx.x; i < 1538; i += 256) wl[i] = w2f[i];
    __syncthreads();
    const int wv = threadIdx.x >> 6, lane = threadIdx.x & 63;
    const int n = blockIdx.x * 4 + wv;
    if (n >= mrows) return;
    float z0 = 0.f, z1 = 0.f;
    const float4 xv = ((const float4*)(X2 + (size_t)(c0 + n) * 256))[lane];
    const float4 a0 = ((const float4*)(Ab + (size_t)n * 512))[lane];
    const float4 a1 = ((const float4*)(Ab + (size_t)n * 512 + 256))[lane];
    const float xa[12] = {xv.x, xv.y, xv.z, xv.w, a0.x, a0.y, a0.z, a0.w,
                          a1.x, a1.y, a1.z, a1.w};
    #pragma unroll
    for (int t = 0; t < 3; ++t) {
        #pragma unroll
        for (int j = 0; j < 4; ++j) {
            const int k = t * 256 + lane * 4 + j;
            z0 = fmaf(xa[t * 4 + j], wl[k * 2], z0);
            z1 = fmaf(xa[t * 4 + j], wl[k * 2 + 1], z1);
        }
    }
    #pragma unroll
    for (int off = 32; off; off >>= 1) {
        z0 += __shfl_down(z0, off, 64);
        z1 += __shfl_down(z1, off, 64);
    }
    if (lane == 0) sel[c0 + n] = (z1 + wl[1537] > z0 + wl[1536]) ? 1 : 0;
}

// ===========================================================================
// weight prep
// ===========================================================================
struct WJ3 { const float* src[4]; unsigned short* dst[4]; int ktot[4]; int koff[4]; };
__global__ __launch_bounds__(256)
void wconv3(WJ3 j) {
    const int job = blockIdx.y;
    const int i = blockIdx.x * 256 + threadIdx.x;   // 256x256
    const int k = i >> 8, n = i & 255;
    const float v = j.src[job][i];
    const unsigned short h1 = f2bf(v);
    const float r1 = v - bf2f(h1);
    const unsigned short h2 = f2bf(r1);
    const float r2 = r1 - bf2f(h2);
    const unsigned short h3 = f2bf(r2);
    const int Kt = j.ktot[job];
    const size_t ps = (size_t)256 * Kt;
    unsigned short* d = j.dst[job] + (size_t)n * Kt + j.koff[job] + k;
    d[0] = h1; d[ps] = h2; d[2 * ps] = h3;
}

struct WJob4 { const float* src[4]; unsigned short* dst[4]; int stride[4]; };
__global__ __launch_bounds__(256)
void wconv_moe(WJob4 j) {
    const int job = blockIdx.y;
    const int i = blockIdx.x * 256 + threadIdx.x;
    const int k = i >> 8, n = i & 255;
    j.dst[job][(size_t)n * j.stride[job] + k] = f2h(j.src[job][i]);
}

// ===========================================================================
extern "C" void kernel_launch(void* const* d_in, const int* in_sizes, int n_in,
                              void* d_out, int out_size, void* d_ws, size_t ws_size,
                              hipStream_t stream) {
    const float* des    = (const float*)d_in[0];
    const float* twt    = (const float*)d_in[1];
    const float* nump   = (const float*)d_in[2];
    const float* catp   = (const float*)d_in[3];
    const int*   ei     = (const int*)d_in[4];
    const int*   et     = (const int*)d_in[5];
    const float* W_in   = (const float*)d_in[6];
    const float* b_in   = (const float*)d_in[7];
    const float* W_rel  = (const float*)d_in[8];
    const float* W_root = (const float*)d_in[9];
    const float* b_rg   = (const float*)d_in[10];
    const float* w_gate = (const float*)d_in[11];
    const float* We1    = (const float*)d_in[12];
    const float* be1    = (const float*)d_in[13];
    const float* We2    = (const float*)d_in[14];
    const float* be2    = (const float*)d_in[15];

    // ---- workspace (~170 MB, under R5's proven 193 MB) ----
    char* ws = (char*)d_ws;
    size_t off = 0;
    float* X1f = (float*)(ws + off); off += (size_t)XROWS * 256 * 4;     // 51.25 MB
    unsigned short* X3h = (unsigned short*)X1f;       // alias: X1 dead after layer-1
    float* X2f = (float*)(ws + off); off += (size_t)XROWS * 256 * 4;     // 51.25 MB
    float* Abf = (float*)(ws + off); off += (size_t)AB_ROWS * 512 * 4;   // 51.25 MB
    unsigned short* H = (unsigned short*)Abf;         // alias: Ab dead after layer-2
    int* cnt   = (int*)(ws + off); off += (size_t)NSEG * 4;
    int* sel   = (int*)(ws + off); off += (size_t)N_NODES * 4;
    int* slots = (int*)(ws + off); off += (size_t)NSEG * CAP * 4;        // 12.8 MB
    unsigned short* wt_in3 = (unsigned short*)(ws + off); off += (size_t)3 * 256 * 256 * 2;
    unsigned short* wt_rg3 = (unsigned short*)(ws + off); off += (size_t)3 * 256 * 768 * 2;
    unsigned short* wt_e1h0 = (unsigned short*)(ws + off); off += 256 * 256 * 2;
    unsigned short* wt_e1h1 = (unsigned short*)(ws + off); off += 256 * 256 * 2;
    unsigned short* wt_e2h  = (unsigned short*)(ws + off); off += 256 * 512 * 2;
    float* w2f = (float*)(ws + off); off += 1538 * 4;

    const dim3 blk(256);

    // ---- CSR build + weight prep + gate fold ----
    hipMemsetAsync(cnt, 0, (size_t)NSEG * 4, stream);
    csr_build<<<(N_EDGES + 255) / 256, blk, 0, stream>>>(ei, et, cnt, slots);
    {
        WJ3 j;
        j.src[0] = W_in;           j.dst[0] = wt_in3; j.ktot[0] = 256; j.koff[0] = 0;
        j.src[1] = W_root;         j.dst[1] = wt_rg3; j.ktot[1] = 768; j.koff[1] = 0;
        j.src[2] = W_rel;          j.dst[2] = wt_rg3; j.ktot[2] = 768; j.koff[2] = 256;
        j.src[3] = W_rel + D * D;  j.dst[3] = wt_rg3; j.ktot[3] = 768; j.koff[3] = 512;
        wconv3<<<dim3(256, 4), blk, 0, stream>>>(j);
    }
    {
        WJob4 j;
        j.src[0] = We1;           j.dst[0] = wt_e1h0;      j.stride[0] = 256;
        j.src[1] = We1 + D * D;   j.dst[1] = wt_e1h1;      j.stride[1] = 256;
        j.src[2] = We2;           j.dst[2] = wt_e2h;       j.stride[2] = 512;
        j.src[3] = We2 + D * D;   j.dst[3] = wt_e2h + 256; j.stride[3] = 512;
        wconv_moe<<<dim3(256, 4), blk, 0, stream>>>(j);
    }
    foldw<<<7, blk, 0, stream>>>(W_root, W_rel, b_rg, w_gate, w2f);

    // ---- stage 1: X1 = selu(concat @ W_in + b_in)  [split-MFMA, direct slabs] ----
    {
        SArgs g{};
        g.sl[0] = {des,  128, 0,   N_NODES};
        g.sl[1] = {twt,  64,  128, N_NODES};
        g.sl[2] = {nump, 32,  192, N_NODES};
        g.sl[3] = {catp, 32,  224, N_NODES};
        g.nslab = 4; g.wt = wt_in3; g.Ktot = 256; g.M = N_NODES;
        g.bias = b_in; g.out = X1f;
        hipLaunchKernelGGL((sgemm<1, 0>), dim3(391, 2), blk, 0, stream, g);
    }

    // ---- RGCN layers, 2 node-chunks each ----
    const int c0s[2] = {0, 25000};
    for (int layer = 0; layer < 2; ++layer) {
        const float* Xl = layer ? X2f : X1f;
        for (int c = 0; c < 2; ++c) {
            const int c0 = c0s[c];
            const int mrows = 25000;
            aggregate<<<(mrows * R + 3) / 4, blk, 0, stream>>>(
                Xl, cnt, slots, Abf, c0 * R, mrows * R);
            SArgs g{};
            g.sl[0] = {Xl + (size_t)c0 * 256, 256, 0,   mrows};
            g.sl[1] = {Abf,                   512, 256, mrows};
            g.sl[2] = {Abf + 256,             512, 512, mrows};
            g.nslab = 3; g.wt = wt_rg3; g.Ktot = 768; g.M = mrows; g.bias = b_rg;
            if (layer == 0) {
                g.out = X2f + (size_t)c0 * 256;
                hipLaunchKernelGGL((sgemm<0, 0>), dim3(196, 2), blk, 0, stream, g);
            } else {
                g.out = X3h + (size_t)c0 * 256;
                hipLaunchKernelGGL((sgemm<0, 1>), dim3(196, 2), blk, 0, stream, g);
                gate2<<<(mrows + 3) / 4, blk, 0, stream>>>(X2f, Abf, w2f, sel, c0, mrows);
            }
        }
    }

    // ---- MoE top-1 (R5-verified path) ----
    for (int e = 0; e < 2; ++e) {
        MArgs g{};
        g.sl[0] = {X3h, (e == 0) ? wt_e1h0 : wt_e1h1, 256, 256, 256};
        g.nslab = 1; g.M = N_NODES;
        g.bias = be1 + e * 256; g.sel = sel; g.expert = e;
        g.out = H + e * 256; g.ldc = 512;
        hipLaunchKernelGGL((mgemm<2, true, false, true>), dim3(M_PAD / 128, 2), blk, 0, stream, g);
    }
    {
        MArgs g{};
        g.sl[0] = {H, wt_e2h, 512, 512, 512};
        g.nslab = 1; g.M = N_NODES;
        g.bias = be2; g.sel = sel;
        g.out = d_out; g.ldc = 256;
        hipLaunchKernelGGL((mgemm<0, false, true, false>), dim3(M_PAD / 128, 2), blk, 0, stream, g);
    }
}

// Round 8
// 492.594 us; speedup vs baseline: 2.0603x; 1.4394x over previous
//
#include <hip/hip_runtime.h>
#include <cstddef>

static constexpr int N_NODES = 50000;
static constexpr int N_EDGES = 400000;
static constexpr int D = 256;
static constexpr int R = 2;
static constexpr int M_PAD = 50048;   // 391 * 128
static constexpr int CAP = 32;
static constexpr int NSEG = N_NODES * R;

typedef _Float16 f16x8 __attribute__((ext_vector_type(8)));
typedef short bf16x8 __attribute__((ext_vector_type(8)));
typedef float f32x4 __attribute__((ext_vector_type(4)));

__device__ __forceinline__ unsigned short f2h(float f) {
    _Float16 h = (_Float16)f;
    return *(unsigned short*)&h;
}
__device__ __forceinline__ float h2f(unsigned short u) {
    _Float16 h = *(_Float16*)&u;
    return (float)h;
}
__device__ __forceinline__ unsigned short f2bf(float f) {
    unsigned u = __float_as_uint(f);
    u += 0x7FFF + ((u >> 16) & 1);          // RNE
    return (unsigned short)(u >> 16);
}
__device__ __forceinline__ float bf2f(unsigned short h) {
    return __uint_as_float((unsigned)h << 16);
}

#define GLOAD16(g, l)                                                          \
    __builtin_amdgcn_global_load_lds(                                          \
        (const __attribute__((address_space(1))) void*)(g),                    \
        (__attribute__((address_space(3))) void*)(l), 16, 0, 0)

// ===========================================================================
// bf16x3 split-MFMA GEMM (R6-VERIFIED, stage-1 only). fp32-grade accuracy.
// ===========================================================================
struct SSlab { const float* x; int xstr; int kstart; int mload; };
struct SArgs {
    SSlab sl[4];
    int nslab;
    const unsigned short* wt;   // 3 planes, plane stride 256*Ktot
    int Ktot;
    int M;
    const float* bias;
    void* out;
};

template<int ACT>
__global__ __launch_bounds__(256, 2)
void sgemm(SArgs a) {
    __shared__ unsigned short As[3][128 * 32];
    __shared__ unsigned short Bs[3][128 * 32];
    const int tid  = threadIdx.x;
    const int wave = tid >> 6, lane = tid & 63;
    const int wm = wave >> 1, wn = wave & 1;
    const int row0 = blockIdx.x * 128;
    const int n0   = blockIdx.y * 128;

    const int arow  = tid >> 1;
    const int ahalf = tid & 1;
    const int br_   = tid >> 2;
    const int bg_   = tid & 3;

    const int gk   = lane >> 4;
    const int frow = lane & 15;
    const int fslot = (gk ^ ((frow >> 1) & 3)) << 3;

    f32x4 acc[4][4] = {};

    for (int ks = 0; ks < a.Ktot; ks += 32) {
        int s = a.nslab - 1;
        while (s > 0 && ks < a.sl[s].kstart) --s;
        const float* xb = a.sl[s].x;
        const int xstr  = a.sl[s].xstr;
        const int kloc  = ks - a.sl[s].kstart;
        const int mload = a.sl[s].mload;

        float ev[16];
        {
            const int gr = row0 + arow;
            if (gr < mload) {
                const float* ap = xb + (size_t)gr * xstr + kloc + ahalf * 16;
                *(float4*)&ev[0]  = ((const float4*)ap)[0];
                *(float4*)&ev[4]  = ((const float4*)ap)[1];
                *(float4*)&ev[8]  = ((const float4*)ap)[2];
                *(float4*)&ev[12] = ((const float4*)ap)[3];
            } else {
                #pragma unroll
                for (int j = 0; j < 16; ++j) ev[j] = 0.f;
            }
        }

        __syncthreads();

        #pragma unroll
        for (int p = 0; p < 3; ++p) {
            #pragma unroll
            for (int q = 0; q < 2; ++q) {
                const int r = q * 64 + br_;
                const int gsrc = (bg_ ^ ((r >> 1) & 3)) << 3;
                GLOAD16(a.wt + (size_t)p * 256 * a.Ktot + (size_t)(n0 + r) * a.Ktot + ks + gsrc,
                        &Bs[p][(q * 64 + wave * 16) * 32]);
            }
        }

        {
            const int sswz = (arow >> 1) & 3;
            #pragma unroll
            for (int g = 0; g < 2; ++g) {
                union { bf16x8 v; unsigned short u[8]; } p1, p2, p3;
                #pragma unroll
                for (int j = 0; j < 8; ++j) {
                    const float v = ev[g * 8 + j];
                    const unsigned short h1 = f2bf(v);
                    const float r1 = v - bf2f(h1);
                    const unsigned short h2 = f2bf(r1);
                    const float r2 = r1 - bf2f(h2);
                    p1.u[j] = h1; p2.u[j] = h2; p3.u[j] = f2bf(r2);
                }
                const int slot = ((ahalf * 2 + g) ^ sswz) << 3;
                *(bf16x8*)&As[0][arow * 32 + slot] = p1.v;
                *(bf16x8*)&As[1][arow * 32 + slot] = p2.v;
                *(bf16x8*)&As[2][arow * 32 + slot] = p3.v;
            }
        }

        __syncthreads();

        bf16x8 bq[4][3];
        #pragma unroll
        for (int n = 0; n < 4; ++n) {
            const int rr = wn * 64 + n * 16 + frow;
            #pragma unroll
            for (int p = 0; p < 3; ++p)
                bq[n][p] = *(const bf16x8*)&Bs[p][rr * 32 + fslot];
        }
        #pragma unroll
        for (int m = 0; m < 4; ++m) {
            const int rr = wm * 64 + m * 16 + frow;
            const bf16x8 a1 = *(const bf16x8*)&As[0][rr * 32 + fslot];
            const bf16x8 a2 = *(const bf16x8*)&As[1][rr * 32 + fslot];
            const bf16x8 a3 = *(const bf16x8*)&As[2][rr * 32 + fslot];
            #pragma unroll
            for (int n = 0; n < 4; ++n) {
                acc[m][n] = __builtin_amdgcn_mfma_f32_16x16x32_bf16(a1, bq[n][0], acc[m][n], 0, 0, 0);
                acc[m][n] = __builtin_amdgcn_mfma_f32_16x16x32_bf16(a1, bq[n][1], acc[m][n], 0, 0, 0);
                acc[m][n] = __builtin_amdgcn_mfma_f32_16x16x32_bf16(a2, bq[n][0], acc[m][n], 0, 0, 0);
                acc[m][n] = __builtin_amdgcn_mfma_f32_16x16x32_bf16(a1, bq[n][2], acc[m][n], 0, 0, 0);
                acc[m][n] = __builtin_amdgcn_mfma_f32_16x16x32_bf16(a3, bq[n][0], acc[m][n], 0, 0, 0);
                acc[m][n] = __builtin_amdgcn_mfma_f32_16x16x32_bf16(a2, bq[n][1], acc[m][n], 0, 0, 0);
            }
        }
    }

    const int erow = (lane >> 4) * 4;
    const int ecol = lane & 15;
    #pragma unroll
    for (int m = 0; m < 4; ++m) {
        #pragma unroll
        for (int r = 0; r < 4; ++r) {
            const int grow = row0 + wm * 64 + m * 16 + erow + r;
            if (grow >= a.M) continue;
            #pragma unroll
            for (int n = 0; n < 4; ++n) {
                const int gcol = n0 + wn * 64 + n * 16 + ecol;
                float v = acc[m][n][r] + a.bias[gcol];
                if (ACT == 1) {
                    const float scale = 1.0507009873554804934f;
                    const float alpha = 1.6732632423543772848f;
                    v = (v > 0.f) ? scale * v : scale * alpha * (expf(v) - 1.f);
                }
                ((float*)a.out)[(size_t)grow * 256 + gcol] = v;
            }
        }
    }
}

// ===========================================================================
// Unified f16 MFMA GEMM (mgemm-verified skeleton).
// A32=true: A slabs are fp32, reg-staged + f16-convert + swizzled ds_write.
// A32=false: A slabs are f16, direct global_load_lds (source-permuted granule).
// EZ: expert from blockIdx.z (weights +ex*65536, bias +ex*256, out col +ex*256).
// ===========================================================================
struct HSlab { const void* x; int xstr; int kstart; };
struct HArgs {
    HSlab sl[3];
    int nslab;
    const unsigned short* wt;   // f16, [256][Ktot] (per expert if EZ)
    int Ktot, M;
    const float* bias;
    const int* sel;
    void* out;
    int ldc;
};

template<int ACT, bool MASK, bool SELB, bool OUTF16, bool A32, bool EZ>
__global__ __launch_bounds__(256, 2)
void hgemm(HArgs a) {
    __shared__ unsigned short As[128 * 64];
    __shared__ unsigned short Bs[128 * 64];
    const int tid  = threadIdx.x;
    const int wave = tid >> 6, lane = tid & 63;
    const int wm = wave >> 1, wn = wave & 1;
    const int row0 = blockIdx.x * 128;
    const int n0   = blockIdx.y * 128;
    const int ex   = EZ ? (int)blockIdx.z : 0;
    const unsigned short* wt = a.wt + (size_t)ex * 65536;
    const float* bias = a.bias + ex * 256;

    const int srow = lane >> 3;
    const int scol = ((lane & 7) ^ (lane >> 3)) << 3;
    const int arow  = tid >> 1;
    const int ahalf = tid & 1;

    f32x4 acc[4][4] = {};

    for (int k0 = 0; k0 < a.Ktot; k0 += 64) {
        int s = a.nslab - 1;
        while (s > 0 && k0 < a.sl[s].kstart) --s;
        const int kloc = k0 - a.sl[s].kstart;
        const int xstr = a.sl[s].xstr;

        float ev[32];
        if (A32) {
            const float* xp = (const float*)a.sl[s].x;
            const float* ap = xp + (size_t)(row0 + arow) * xstr + kloc + ahalf * 32;
            #pragma unroll
            for (int q = 0; q < 8; ++q)
                *(float4*)&ev[q * 4] = ((const float4*)ap)[q];
        }

        __syncthreads();

        if (!A32) {
            const unsigned short* xp = (const unsigned short*)a.sl[s].x;
            #pragma unroll
            for (int i = 0; i < 4; ++i) {
                const int r = wave * 32 + i * 8;
                GLOAD16(xp + (size_t)(row0 + r + srow) * xstr + kloc + scol, &As[r * 64]);
            }
        }
        #pragma unroll
        for (int i = 0; i < 4; ++i) {
            const int r = wave * 32 + i * 8;
            GLOAD16(wt + (size_t)(n0 + r + srow) * a.Ktot + k0 + scol, &Bs[r * 64]);
        }
        if (A32) {
            #pragma unroll
            for (int gi = 0; gi < 4; ++gi) {
                const int sgr = ahalf * 4 + gi;      // source granule 0..7
                union { f16x8 v; _Float16 h[8]; } pk;
                #pragma unroll
                for (int j = 0; j < 8; ++j) pk.h[j] = (_Float16)ev[gi * 8 + j];
                *(f16x8*)&As[arow * 64 + ((sgr ^ (arow & 7)) << 3)] = pk.v;
            }
        }

        __syncthreads();

        #pragma unroll
        for (int kk = 0; kk < 2; ++kk) {
            const int gkk = kk * 4 + (lane >> 4);
            f16x8 af[4], bfr[4];
            #pragma unroll
            for (int m = 0; m < 4; ++m) {
                const int rr = wm * 64 + m * 16 + (lane & 15);
                af[m] = *(const f16x8*)&As[rr * 64 + ((gkk ^ (rr & 7)) << 3)];
            }
            #pragma unroll
            for (int n = 0; n < 4; ++n) {
                const int rr = wn * 64 + n * 16 + (lane & 15);
                bfr[n] = *(const f16x8*)&Bs[rr * 64 + ((gkk ^ (rr & 7)) << 3)];
            }
            #pragma unroll
            for (int m = 0; m < 4; ++m)
                #pragma unroll
                for (int n = 0; n < 4; ++n)
                    acc[m][n] = __builtin_amdgcn_mfma_f32_16x16x32_f16(
                        af[m], bfr[n], acc[m][n], 0, 0, 0);
        }
    }

    const int erow = (lane >> 4) * 4;
    const int ecol = lane & 15;
    #pragma unroll
    for (int m = 0; m < 4; ++m) {
        #pragma unroll
        for (int r = 0; r < 4; ++r) {
            const int grow = row0 + wm * 64 + m * 16 + erow + r;
            if (grow >= a.M) continue;
            int sv = 0;
            if (MASK || SELB) sv = a.sel[grow];
            #pragma unroll
            for (int n = 0; n < 4; ++n) {
                const int gcol = n0 + wn * 64 + n * 16 + ecol;
                const float b = SELB ? a.bias[sv * 256 + gcol] : bias[gcol];
                float v = acc[m][n][r] + b;
                if (ACT == 2) v = (v >= 0.f) ? v : 0.01f * v;
                if (MASK && sv != ex) v = 0.f;
                const size_t oidx = (size_t)grow * a.ldc + (EZ ? ex * 256 : 0) + gcol;
                if (OUTF16) ((unsigned short*)a.out)[oidx] = f2h(v);
                else        ((float*)a.out)[oidx] = v;
            }
        }
    }
}

// ===========================================================================
// bucket-CSR build (verified)
// ===========================================================================
__global__ __launch_bounds__(256)
void csr_build(const int* __restrict__ ei, const int* __restrict__ et,
               int* cnt, int* slots) {
    const int e = blockIdx.x * 256 + threadIdx.x;
    if (e >= N_EDGES) return;
    const int src = ei[e];
    const int dst = ei[N_EDGES + e];
    const int seg = dst * R + et[e];
    const int slot = atomicAdd(&cnt[seg], 1);
    if (slot < CAP) slots[(size_t)seg * CAP + slot] = src;
}

// fp32 aggregate (verified): mean of X rows -> Ab[(node)*512 + r*256 + d]
__global__ __launch_bounds__(256)
void aggregate(const float* __restrict__ X, const int* __restrict__ cnt,
               const int* __restrict__ slots, float* __restrict__ Ab,
               int seg0, int nseg) {
    const int w = blockIdx.x * 4 + (threadIdx.x >> 6);
    if (w >= nseg) return;
    const int lane = threadIdx.x & 63;
    const int s = seg0 + w;
    const int m = min(cnt[s], CAP);
    const int* sl = slots + (size_t)s * CAP;
    float4 acc = make_float4(0.f, 0.f, 0.f, 0.f);
    for (int i = 0; i < m; ++i) {
        const float4 v = *(const float4*)(X + (size_t)sl[i] * 256 + lane * 4);
        acc.x += v.x; acc.y += v.y; acc.z += v.z; acc.w += v.w;
    }
    const float inv = (m > 0) ? 1.0f / (float)m : 0.0f;
    acc.x *= inv; acc.y *= inv; acc.z *= inv; acc.w *= inv;
    *(float4*)(Ab + (size_t)(w >> 1) * 512 + (w & 1) * 256 + lane * 4) = acc;
}

// f16 aggregate: gather f16 rows, fp32 accum, f16 out
__global__ __launch_bounds__(256)
void agg_h(const unsigned short* __restrict__ Xh, const int* __restrict__ cnt,
           const int* __restrict__ slots, unsigned short* __restrict__ Abh) {
    const int w = blockIdx.x * 4 + (threadIdx.x >> 6);
    if (w >= NSEG) return;
    const int lane = threadIdx.x & 63;
    const int m = min(cnt[w], CAP);
    const int* sl = slots + (size_t)w * CAP;
    float ac[4] = {};
    for (int i = 0; i < m; ++i) {
        const ushort4 v = *(const ushort4*)(Xh + (size_t)sl[i] * 256 + lane * 4);
        ac[0] += h2f(v.x); ac[1] += h2f(v.y); ac[2] += h2f(v.z); ac[3] += h2f(v.w);
    }
    const float inv = (m > 0) ? 1.0f / (float)m : 0.0f;
    ushort4 o = make_ushort4(f2h(ac[0] * inv), f2h(ac[1] * inv),
                             f2h(ac[2] * inv), f2h(ac[3] * inv));
    *(ushort4*)(Abh + (size_t)(w >> 1) * 512 + (w & 1) * 256 + lane * 4) = o;
}

// ===========================================================================
// Exact gate pipeline (all fp32, from fp32-exact X1/Ab1):
// logits[n] = vu[n,0:2] + cb[0:2] + c3 + M0(vu[:,2:4])|n + d0*cb[2:4]
//                                     + M1(vu[:,4:6])|n + d1*cb[4:6]
// ===========================================================================
// fold1: wfold[d][2c+j] = Wc[d,:]@wg[:,j]  (c: 0=W_root,1=Wrel0,2=Wrel1); c3 = b_rg@wg
__global__ __launch_bounds__(256)
void fold1(const float* __restrict__ W_root, const float* __restrict__ W_rel,
           const float* __restrict__ b_rg, const float* __restrict__ wg,
           float* __restrict__ wfold, float* __restrict__ c3) {
    const int idx = blockIdx.x * 256 + threadIdx.x;
    if (idx < 1536) {
        const int d = idx / 6, jj = idx % 6, c = jj >> 1, j = jj & 1;
        const float* row = (c == 0) ? W_root + (size_t)d * 256
                                    : W_rel + (size_t)(c - 1) * 65536 + (size_t)d * 256;
        float s = 0.f;
        for (int e = 0; e < 256; ++e) s += row[e] * wg[e * 2 + j];
        wfold[idx] = s;
    } else if (idx < 1538) {
        const int j = idx - 1536;
        float s = 0.f;
        for (int e = 0; e < 256; ++e) s += b_rg[e] * wg[e * 2 + j];
        c3[j] = s;
    }
}

// fold2: W6[k][j] = Wall[k,:]@wfold[:,j]  (Wall rows: W_root then Wrel0 then Wrel1)
//        cb[j] = b_rg@wfold[:,j]
__global__ __launch_bounds__(256)
void fold2(const float* __restrict__ W_root, const float* __restrict__ W_rel,
           const float* __restrict__ b_rg, const float* __restrict__ wfold,
           float* __restrict__ W6, float* __restrict__ cb) {
    const int idx = blockIdx.x * 256 + threadIdx.x;
    if (idx < 4608) {
        const int k = idx / 6, j = idx % 6;
        const float* row = (k < 256) ? W_root + (size_t)k * 256
                                     : W_rel + (size_t)(k - 256) * 256;
        float s = 0.f;
        for (int d = 0; d < 256; ++d) s += row[d] * wfold[d * 6 + j];
        W6[idx] = s;
    } else if (idx < 4614) {
        const int j = idx - 4608;
        float s = 0.f;
        for (int d = 0; d < 256; ++d) s += b_rg[d] * wfold[d * 6 + j];
        cb[j] = s;
    }
}

// vu = [X1 | Ab1] @ W6   (N x 6), wave per node
__global__ __launch_bounds__(256)
void vu_kernel(const float* __restrict__ X1, const float* __restrict__ Ab,
               const float* __restrict__ W6, float* __restrict__ VU, int M) {
    __shared__ float wl[768 * 6];
    for (int i = threadIdx.x; i < 768 * 6; i += 256) wl[i] = W6[i];
    __syncthreads();
    const int wave = threadIdx.x >> 6, lane = threadIdx.x & 63;
    const int n = blockIdx.x * 4 + wave;
    if (n >= M) return;
    const float4 xv = ((const float4*)(X1 + (size_t)n * 256))[lane];
    const float4 a0 = ((const float4*)(Ab + (size_t)n * 512))[lane];
    const float4 a1 = ((const float4*)(Ab + (size_t)n * 512))[lane + 64];
    const float xa[12] = {xv.x, xv.y, xv.z, xv.w, a0.x, a0.y, a0.z, a0.w,
                          a1.x, a1.y, a1.z, a1.w};
    float z[6] = {};
    #pragma unroll
    for (int t = 0; t < 3; ++t)
        #pragma unroll
        for (int i = 0; i < 4; ++i) {
            const int k = t * 256 + lane * 4 + i;
            #pragma unroll
            for (int j = 0; j < 6; ++j) z[j] = fmaf(xa[t * 4 + i], wl[k * 6 + j], z[j]);
        }
    #pragma unroll
    for (int off = 32; off; off >>= 1)
        #pragma unroll
        for (int j = 0; j < 6; ++j) z[j] += __shfl_down(z[j], off, 64);
    if (lane == 0) {
        #pragma unroll
        for (int j = 0; j < 6; ++j) VU[(size_t)n * 6 + j] = z[j];
    }
}

// sel[n] from vu + 2-dim CSR gather
__global__ __launch_bounds__(256)
void u_gate(const float* __restrict__ VU, const int* __restrict__ cnt,
            const int* __restrict__ slots, const float* __restrict__ cb,
            const float* __restrict__ c3, int* __restrict__ sel, int M) {
    const int n = blockIdx.x * 256 + threadIdx.x;
    if (n >= M) return;
    float z0 = VU[(size_t)n * 6 + 0] + cb[0] + c3[0];
    float z1 = VU[(size_t)n * 6 + 1] + cb[1] + c3[1];
    #pragma unroll
    for (int r = 0; r < 2; ++r) {
        const int seg = n * 2 + r;
        const int m = min(cnt[seg], CAP);
        if (m > 0) {
            const int* sl = slots + (size_t)seg * CAP;
            float s0 = 0.f, s1 = 0.f;
            for (int i = 0; i < m; ++i) {
                const int src = sl[i];
                s0 += VU[(size_t)src * 6 + 2 + 2 * r];
                s1 += VU[(size_t)src * 6 + 3 + 2 * r];
            }
            const float inv = 1.0f / (float)m;
            z0 += s0 * inv + cb[2 + 2 * r];
            z1 += s1 * inv + cb[3 + 2 * r];
        }
    }
    sel[n] = (z1 > z0) ? 1 : 0;
}

// ===========================================================================
// weight prep
// ===========================================================================
struct WJ3 { const float* src[4]; unsigned short* dst[4]; int ktot[4]; int koff[4]; };
__global__ __launch_bounds__(256)
void wconv3(WJ3 j) {
    const int job = blockIdx.y;
    const int i = blockIdx.x * 256 + threadIdx.x;
    const int k = i >> 8, n = i & 255;
    const float v = j.src[job][i];
    const unsigned short h1 = f2bf(v);
    const float r1 = v - bf2f(h1);
    const unsigned short h2 = f2bf(r1);
    const float r2 = r1 - bf2f(h2);
    const unsigned short h3 = f2bf(r2);
    const int Kt = j.ktot[job];
    const size_t ps = (size_t)256 * Kt;
    unsigned short* d = j.dst[job] + (size_t)n * Kt + j.koff[job] + k;
    d[0] = h1; d[ps] = h2; d[2 * ps] = h3;
}

struct WJH { const float* src[8]; unsigned short* dst[8]; int stride[8]; int koff[8]; };
__global__ __launch_bounds__(256)
void wconv_h(WJH j) {
    const int job = blockIdx.y;
    const int i = blockIdx.x * 256 + threadIdx.x;
    const int k = i >> 8, n = i & 255;
    j.dst[job][(size_t)n * j.stride[job] + j.koff[job] + k] = f2h(j.src[job][i]);
}

// ===========================================================================
extern "C" void kernel_launch(void* const* d_in, const int* in_sizes, int n_in,
                              void* d_out, int out_size, void* d_ws, size_t ws_size,
                              hipStream_t stream) {
    const float* des    = (const float*)d_in[0];
    const float* twt    = (const float*)d_in[1];
    const float* nump   = (const float*)d_in[2];
    const float* catp   = (const float*)d_in[3];
    const int*   ei     = (const int*)d_in[4];
    const int*   et     = (const int*)d_in[5];
    const float* W_in   = (const float*)d_in[6];
    const float* b_in   = (const float*)d_in[7];
    const float* W_rel  = (const float*)d_in[8];
    const float* W_root = (const float*)d_in[9];
    const float* b_rg   = (const float*)d_in[10];
    const float* w_gate = (const float*)d_in[11];
    const float* We1    = (const float*)d_in[12];
    const float* be1    = (const float*)d_in[13];
    const float* We2    = (const float*)d_in[14];
    const float* be2    = (const float*)d_in[15];

    // ---- workspace (~195 MB) ----
    char* ws = (char*)d_ws;
    size_t off = 0;
    auto alloc = [&](size_t bytes) { char* p = ws + off; off += (bytes + 255) & ~(size_t)255; return p; };
    float* X1f  = (float*)alloc((size_t)M_PAD * 256 * 4);      // 51.25 MB
    char*  regA = alloc((size_t)M_PAD * 512 * 4);              // 102.5 MB: Ab1f | Ab2h | H
    unsigned short* X2h = (unsigned short*)alloc((size_t)M_PAD * 256 * 2);  // 25.6 MB
    float* VU   = (float*)alloc((size_t)N_NODES * 6 * 4);
    int*   cnt  = (int*)alloc((size_t)NSEG * 4);
    int*   sel  = (int*)alloc((size_t)N_NODES * 4);
    int*   slots= (int*)alloc((size_t)NSEG * CAP * 4);         // 12.8 MB
    unsigned short* wt_in3 = (unsigned short*)alloc((size_t)3 * 65536 * 2);
    unsigned short* wt_rg  = (unsigned short*)alloc((size_t)256 * 768 * 2);
    unsigned short* wt_e1  = (unsigned short*)alloc((size_t)2 * 65536 * 2);
    unsigned short* wt_e2  = (unsigned short*)alloc((size_t)256 * 512 * 2);
    float* wfold = (float*)alloc(256 * 6 * 4);
    float* c3    = (float*)alloc(8);
    float* W6    = (float*)alloc(768 * 6 * 4);
    float* cb    = (float*)alloc(24);

    float* Ab1f = (float*)regA;                                   // fp32, layer-1
    unsigned short* Ab2h = (unsigned short*)regA;                 // f16, layer-2 (after Ab1f dead)
    unsigned short* H    = (unsigned short*)(regA + (size_t)M_PAD * 256 * 4); // f16 MoE h1
    unsigned short* X3h  = (unsigned short*)X1f;                  // f16, after X1f dead

    const dim3 blk(256);

    // ---- prep ----
    hipMemsetAsync(cnt, 0, (size_t)NSEG * 4, stream);
    csr_build<<<(N_EDGES + 255) / 256, blk, 0, stream>>>(ei, et, cnt, slots);
    {
        WJ3 j{};
        j.src[0] = W_in; j.dst[0] = wt_in3; j.ktot[0] = 256; j.koff[0] = 0;
        wconv3<<<dim3(256, 1), blk, 0, stream>>>(j);
    }
    {
        WJH j{};
        j.src[0] = W_root;         j.dst[0] = wt_rg;         j.stride[0] = 768; j.koff[0] = 0;
        j.src[1] = W_rel;          j.dst[1] = wt_rg;         j.stride[1] = 768; j.koff[1] = 256;
        j.src[2] = W_rel + 65536;  j.dst[2] = wt_rg;         j.stride[2] = 768; j.koff[2] = 512;
        j.src[3] = We1;            j.dst[3] = wt_e1;         j.stride[3] = 256; j.koff[3] = 0;
        j.src[4] = We1 + 65536;    j.dst[4] = wt_e1 + 65536; j.stride[4] = 256; j.koff[4] = 0;
        j.src[5] = We2;            j.dst[5] = wt_e2;         j.stride[5] = 512; j.koff[5] = 0;
        j.src[6] = We2 + 65536;    j.dst[6] = wt_e2;         j.stride[6] = 512; j.koff[6] = 256;
        wconv_h<<<dim3(256, 7), blk, 0, stream>>>(j);
    }
    fold1<<<7, blk, 0, stream>>>(W_root, W_rel, b_rg, w_gate, wfold, c3);
    fold2<<<19, blk, 0, stream>>>(W_root, W_rel, b_rg, wfold, W6, cb);

    // ---- stage 1: X1f = selu(concat @ W_in + b_in)  [bf16x3, fp32-grade] ----
    {
        SArgs g{};
        g.sl[0] = {des,  128, 0,   N_NODES};
        g.sl[1] = {twt,  64,  128, N_NODES};
        g.sl[2] = {nump, 32,  192, N_NODES};
        g.sl[3] = {catp, 32,  224, N_NODES};
        g.nslab = 4; g.wt = wt_in3; g.Ktot = 256; g.M = N_NODES;
        g.bias = b_in; g.out = X1f;
        hipLaunchKernelGGL((sgemm<1>), dim3(391, 2), blk, 0, stream, g);
    }

    // ---- layer-1 aggregate (fp32, full M) ----
    aggregate<<<(NSEG + 3) / 4, blk, 0, stream>>>(X1f, cnt, slots, Ab1f, 0, NSEG);

    // ---- exact gate pipeline (fp32) ----
    vu_kernel<<<(N_NODES + 3) / 4, blk, 0, stream>>>(X1f, Ab1f, W6, VU, N_NODES);
    u_gate<<<(N_NODES + 255) / 256, blk, 0, stream>>>(VU, cnt, slots, cb, c3, sel, N_NODES);

    // ---- layer 1: X2h = [X1f|Ab1f] @ W_all + b   (f16 MFMA, fp32-cvt A) ----
    {
        HArgs g{};
        g.sl[0] = {X1f,        256, 0};
        g.sl[1] = {Ab1f,       512, 256};
        g.sl[2] = {Ab1f + 256, 512, 512};
        g.nslab = 3; g.wt = wt_rg; g.Ktot = 768; g.M = N_NODES;
        g.bias = b_rg; g.out = X2h; g.ldc = 256;
        hipLaunchKernelGGL((hgemm<0, false, false, true, true, false>),
                           dim3(391, 2), blk, 0, stream, g);
    }

    // ---- layer-2 aggregate (f16) ----
    agg_h<<<(NSEG + 3) / 4, blk, 0, stream>>>(X2h, cnt, slots, Ab2h);

    // ---- layer 2: X3h = [X2h|Ab2h] @ W_all + b   (f16 direct) ----
    {
        HArgs g{};
        g.sl[0] = {X2h,        256, 0};
        g.sl[1] = {Ab2h,       512, 256};
        g.sl[2] = {Ab2h + 256, 512, 512};
        g.nslab = 3; g.wt = wt_rg; g.Ktot = 768; g.M = N_NODES;
        g.bias = b_rg; g.out = X3h; g.ldc = 256;
        hipLaunchKernelGGL((hgemm<0, false, false, true, false, false>),
                           dim3(391, 2), blk, 0, stream, g);
    }

    // ---- MoE h1, both experts fused (blockIdx.z)  [FIX R8: grid.y = 2] ----
    {
        HArgs g{};
        g.sl[0] = {X3h, 256, 0};
        g.nslab = 1; g.wt = wt_e1; g.Ktot = 256; g.M = N_NODES;
        g.bias = be1; g.sel = sel; g.out = H; g.ldc = 512;
        hipLaunchKernelGGL((hgemm<2, true, false, true, false, true>),
                           dim3(391, 2, 2), blk, 0, stream, g);
    }

    // ---- MoE out: d_out = H @ wt_e2 + be2[sel] ----
    {
        HArgs g{};
        g.sl[0] = {H, 512, 0};
        g.nslab = 1; g.wt = wt_e2; g.Ktot = 512; g.M = N_NODES;
        g.bias = be2; g.sel = sel; g.out = d_out; g.ldc = 256;
        hipLaunchKernelGGL((hgemm<0, false, true, false, false, false>),
                           dim3(391, 2), blk, 0, stream, g);
    }
}

// Round 9
// 476.568 us; speedup vs baseline: 2.1296x; 1.0336x over previous
//
#include <hip/hip_runtime.h>
#include <cstddef>

static constexpr int N_NODES = 50000;
static constexpr int N_EDGES = 400000;
static constexpr int D = 256;
static constexpr int R = 2;
static constexpr int M_PAD = 50048;   // 391 * 128
static constexpr int CAP = 32;
static constexpr int NSEG = N_NODES * R;

typedef _Float16 f16x8 __attribute__((ext_vector_type(8)));
typedef float f32x4 __attribute__((ext_vector_type(4)));

__device__ __forceinline__ unsigned short f2h(float f) {
    _Float16 h = (_Float16)f;
    return *(unsigned short*)&h;
}
__device__ __forceinline__ float h2f(unsigned short u) {
    _Float16 h = *(_Float16*)&u;
    return (float)h;
}

#define GLOAD16(g, l)                                                          \
    __builtin_amdgcn_global_load_lds(                                          \
        (const __attribute__((address_space(1))) void*)(g),                    \
        (__attribute__((address_space(3))) void*)(l), 16, 0, 0)

// ===========================================================================
// f16x2 split-MFMA GEMM (stage-1): fp32-grade via scaled-residual Dekker.
// v = h1 + h2'/2048  (h1=(f16)v, h2'=(f16)((v-h1)*2048); all steps exact or
// 2^-24-grade).  Products: acc0 += h1A*h1B;  accC += h1A*h2B' + h2A'*h1B;
// result = acc0 + accC/2048.  Dropped h2h2 ~ 2^-24|vw|.  Gate-safe (R5 class).
// Skeleton (staging/swizzle/epilogue) = R6-verified sgemm, planes 3->2.
// ===========================================================================
struct SSlab { const float* x; int xstr; int kstart; int mload; };
struct SArgs {
    SSlab sl[4];
    int nslab;
    const unsigned short* wt;   // 2 f16 planes, plane stride 256*Ktot
    int Ktot;
    int M;
    const float* bias;
    void* out;
};

template<int ACT>
__global__ __launch_bounds__(256, 2)
void sgemm(SArgs a) {
    __shared__ unsigned short As[2][128 * 32];
    __shared__ unsigned short Bs[2][128 * 32];
    const int tid  = threadIdx.x;
    const int wave = tid >> 6, lane = tid & 63;
    const int wm = wave >> 1, wn = wave & 1;
    const int row0 = blockIdx.x * 128;
    const int n0   = blockIdx.y * 128;

    const int arow  = tid >> 1;
    const int ahalf = tid & 1;
    const int br_   = tid >> 2;
    const int bg_   = tid & 3;

    const int gk   = lane >> 4;
    const int frow = lane & 15;
    const int fslot = (gk ^ ((frow >> 1) & 3)) << 3;

    f32x4 acc0[4][4] = {};
    f32x4 accC[4][4] = {};

    for (int ks = 0; ks < a.Ktot; ks += 32) {
        int s = a.nslab - 1;
        while (s > 0 && ks < a.sl[s].kstart) --s;
        const float* xb = a.sl[s].x;
        const int xstr  = a.sl[s].xstr;
        const int kloc  = ks - a.sl[s].kstart;
        const int mload = a.sl[s].mload;

        float ev[16];
        {
            const int gr = row0 + arow;
            if (gr < mload) {
                const float* ap = xb + (size_t)gr * xstr + kloc + ahalf * 16;
                *(float4*)&ev[0]  = ((const float4*)ap)[0];
                *(float4*)&ev[4]  = ((const float4*)ap)[1];
                *(float4*)&ev[8]  = ((const float4*)ap)[2];
                *(float4*)&ev[12] = ((const float4*)ap)[3];
            } else {
                #pragma unroll
                for (int j = 0; j < 16; ++j) ev[j] = 0.f;
            }
        }

        __syncthreads();

        #pragma unroll
        for (int p = 0; p < 2; ++p) {
            #pragma unroll
            for (int q = 0; q < 2; ++q) {
                const int r = q * 64 + br_;
                const int gsrc = (bg_ ^ ((r >> 1) & 3)) << 3;
                GLOAD16(a.wt + (size_t)p * 256 * a.Ktot + (size_t)(n0 + r) * a.Ktot + ks + gsrc,
                        &Bs[p][(q * 64 + wave * 16) * 32]);
            }
        }

        {
            const int sswz = (arow >> 1) & 3;
            #pragma unroll
            for (int g = 0; g < 2; ++g) {
                union { f16x8 v; _Float16 h[8]; } p1, p2;
                #pragma unroll
                for (int j = 0; j < 8; ++j) {
                    const float v = ev[g * 8 + j];
                    const _Float16 h1 = (_Float16)v;
                    const float r1 = (v - (float)h1) * 2048.0f;
                    p1.h[j] = h1; p2.h[j] = (_Float16)r1;
                }
                const int slot = ((ahalf * 2 + g) ^ sswz) << 3;
                *(f16x8*)&As[0][arow * 32 + slot] = p1.v;
                *(f16x8*)&As[1][arow * 32 + slot] = p2.v;
            }
        }

        __syncthreads();

        f16x8 bq[4][2];
        #pragma unroll
        for (int n = 0; n < 4; ++n) {
            const int rr = wn * 64 + n * 16 + frow;
            #pragma unroll
            for (int p = 0; p < 2; ++p)
                bq[n][p] = *(const f16x8*)&Bs[p][rr * 32 + fslot];
        }
        #pragma unroll
        for (int m = 0; m < 4; ++m) {
            const int rr = wm * 64 + m * 16 + frow;
            const f16x8 a1 = *(const f16x8*)&As[0][rr * 32 + fslot];
            const f16x8 a2 = *(const f16x8*)&As[1][rr * 32 + fslot];
            #pragma unroll
            for (int n = 0; n < 4; ++n) {
                acc0[m][n] = __builtin_amdgcn_mfma_f32_16x16x32_f16(a1, bq[n][0], acc0[m][n], 0, 0, 0);
                accC[m][n] = __builtin_amdgcn_mfma_f32_16x16x32_f16(a1, bq[n][1], accC[m][n], 0, 0, 0);
                accC[m][n] = __builtin_amdgcn_mfma_f32_16x16x32_f16(a2, bq[n][0], accC[m][n], 0, 0, 0);
            }
        }
    }

    const int erow = (lane >> 4) * 4;
    const int ecol = lane & 15;
    #pragma unroll
    for (int m = 0; m < 4; ++m) {
        #pragma unroll
        for (int r = 0; r < 4; ++r) {
            const int grow = row0 + wm * 64 + m * 16 + erow + r;
            if (grow >= a.M) continue;
            #pragma unroll
            for (int n = 0; n < 4; ++n) {
                const int gcol = n0 + wn * 64 + n * 16 + ecol;
                float v = acc0[m][n][r] + accC[m][n][r] * (1.0f / 2048.0f) + a.bias[gcol];
                if (ACT == 1) {
                    const float scale = 1.0507009873554804934f;
                    const float alpha = 1.6732632423543772848f;
                    v = (v > 0.f) ? scale * v : scale * alpha * (expf(v) - 1.f);
                }
                ((float*)a.out)[(size_t)grow * 256 + gcol] = v;
            }
        }
    }
}

// ===========================================================================
// Unified f16 MFMA GEMM (R8-verified skeleton).
// A32: A slabs fp32, reg-staged + f16-convert + swizzled ds_write.
// EZ:  expert from blockIdx.z (weights +ex*65536, bias +ex*256).
// PERM: A-rows gathered via perm[base+row], C-rows scattered to perm row;
//       expert row-range from c01 (expert0: [0,c0), expert1: [c0,M)).
// ===========================================================================
struct HSlab { const void* x; int xstr; int kstart; };
struct HArgs {
    HSlab sl[3];
    int nslab;
    const unsigned short* wt;
    int Ktot, M;
    const float* bias;
    const int* sel;
    const int* perm;
    const int* c01;
    void* out;
    int ldc;
};

template<int ACT, bool MASK, bool SELB, bool OUTF16, bool A32, bool EZ, bool PERM>
__global__ __launch_bounds__(256, 2)
void hgemm(HArgs a) {
    __shared__ unsigned short As[128 * 64];
    __shared__ unsigned short Bs[128 * 64];
    const int tid  = threadIdx.x;
    const int wave = tid >> 6, lane = tid & 63;
    const int wm = wave >> 1, wn = wave & 1;
    const int row0 = blockIdx.x * 128;
    const int n0   = blockIdx.y * 128;
    const int ex   = EZ ? (int)blockIdx.z : 0;
    const unsigned short* wt = a.wt + (size_t)ex * 65536;
    const float* bias = a.bias + ex * 256;

    int cntE = 0, base = 0;
    if (PERM) {
        const int c0 = a.c01[0];
        cntE = (ex == 0) ? c0 : a.M - c0;
        base = (ex == 0) ? 0 : c0;
        if (row0 >= cntE) return;
    }

    const int srow = lane >> 3;
    const int scol = ((lane & 7) ^ (lane >> 3)) << 3;
    const int arow  = tid >> 1;
    const int ahalf = tid & 1;

    f32x4 acc[4][4] = {};

    for (int k0 = 0; k0 < a.Ktot; k0 += 64) {
        int s = a.nslab - 1;
        while (s > 0 && k0 < a.sl[s].kstart) --s;
        const int kloc = k0 - a.sl[s].kstart;
        const int xstr = a.sl[s].xstr;

        float ev[32];
        if (A32) {
            const float* xp = (const float*)a.sl[s].x;
            const float* ap = xp + (size_t)(row0 + arow) * xstr + kloc + ahalf * 32;
            #pragma unroll
            for (int q = 0; q < 8; ++q)
                *(float4*)&ev[q * 4] = ((const float4*)ap)[q];
        }

        __syncthreads();

        if (!A32) {
            const unsigned short* xp = (const unsigned short*)a.sl[s].x;
            #pragma unroll
            for (int i = 0; i < 4; ++i) {
                const int r = wave * 32 + i * 8;
                int lr = row0 + r + srow;
                if (PERM) lr = a.perm[base + (lr < cntE ? lr : cntE - 1)];
                GLOAD16(xp + (size_t)lr * xstr + kloc + scol, &As[r * 64]);
            }
        }
        #pragma unroll
        for (int i = 0; i < 4; ++i) {
            const int r = wave * 32 + i * 8;
            GLOAD16(wt + (size_t)(n0 + r + srow) * a.Ktot + k0 + scol, &Bs[r * 64]);
        }
        if (A32) {
            #pragma unroll
            for (int gi = 0; gi < 4; ++gi) {
                const int sgr = ahalf * 4 + gi;
                union { f16x8 v; _Float16 h[8]; } pk;
                #pragma unroll
                for (int j = 0; j < 8; ++j) pk.h[j] = (_Float16)ev[gi * 8 + j];
                *(f16x8*)&As[arow * 64 + ((sgr ^ (arow & 7)) << 3)] = pk.v;
            }
        }

        __syncthreads();

        #pragma unroll
        for (int kk = 0; kk < 2; ++kk) {
            const int gkk = kk * 4 + (lane >> 4);
            f16x8 af[4], bfr[4];
            #pragma unroll
            for (int m = 0; m < 4; ++m) {
                const int rr = wm * 64 + m * 16 + (lane & 15);
                af[m] = *(const f16x8*)&As[rr * 64 + ((gkk ^ (rr & 7)) << 3)];
            }
            #pragma unroll
            for (int n = 0; n < 4; ++n) {
                const int rr = wn * 64 + n * 16 + (lane & 15);
                bfr[n] = *(const f16x8*)&Bs[rr * 64 + ((gkk ^ (rr & 7)) << 3)];
            }
            #pragma unroll
            for (int m = 0; m < 4; ++m)
                #pragma unroll
                for (int n = 0; n < 4; ++n)
                    acc[m][n] = __builtin_amdgcn_mfma_f32_16x16x32_f16(
                        af[m], bfr[n], acc[m][n], 0, 0, 0);
        }
    }

    const int erow = (lane >> 4) * 4;
    const int ecol = lane & 15;
    #pragma unroll
    for (int m = 0; m < 4; ++m) {
        #pragma unroll
        for (int r = 0; r < 4; ++r) {
            const int grow = row0 + wm * 64 + m * 16 + erow + r;
            if (PERM) { if (grow >= cntE) continue; }
            else      { if (grow >= a.M) continue; }
            const int orow = PERM ? a.perm[base + grow] : grow;
            int sv = 0;
            if (MASK || SELB) sv = a.sel[orow];
            #pragma unroll
            for (int n = 0; n < 4; ++n) {
                const int gcol = n0 + wn * 64 + n * 16 + ecol;
                const float b = SELB ? a.bias[sv * 256 + gcol] : bias[gcol];
                float v = acc[m][n][r] + b;
                if (ACT == 2) v = (v >= 0.f) ? v : 0.01f * v;
                if (MASK && sv != ex) v = 0.f;
                const size_t oidx = (size_t)orow * a.ldc + ((EZ && !PERM) ? ex * 256 : 0) + gcol;
                if (OUTF16) ((unsigned short*)a.out)[oidx] = f2h(v);
                else        ((float*)a.out)[oidx] = v;
            }
        }
    }
}

// ===========================================================================
// bucket-CSR build (verified)
// ===========================================================================
__global__ __launch_bounds__(256)
void csr_build(const int* __restrict__ ei, const int* __restrict__ et,
               int* cnt, int* slots) {
    const int e = blockIdx.x * 256 + threadIdx.x;
    if (e >= N_EDGES) return;
    const int src = ei[e];
    const int dst = ei[N_EDGES + e];
    const int seg = dst * R + et[e];
    const int slot = atomicAdd(&cnt[seg], 1);
    if (slot < CAP) slots[(size_t)seg * CAP + slot] = src;
}

// fp32 aggregate (verified)
__global__ __launch_bounds__(256)
void aggregate(const float* __restrict__ X, const int* __restrict__ cnt,
               const int* __restrict__ slots, float* __restrict__ Ab,
               int seg0, int nseg) {
    const int w = blockIdx.x * 4 + (threadIdx.x >> 6);
    if (w >= nseg) return;
    const int lane = threadIdx.x & 63;
    const int s = seg0 + w;
    const int m = min(cnt[s], CAP);
    const int* sl = slots + (size_t)s * CAP;
    float4 acc = make_float4(0.f, 0.f, 0.f, 0.f);
    for (int i = 0; i < m; ++i) {
        const float4 v = *(const float4*)(X + (size_t)sl[i] * 256 + lane * 4);
        acc.x += v.x; acc.y += v.y; acc.z += v.z; acc.w += v.w;
    }
    const float inv = (m > 0) ? 1.0f / (float)m : 0.0f;
    acc.x *= inv; acc.y *= inv; acc.z *= inv; acc.w *= inv;
    *(float4*)(Ab + (size_t)(w >> 1) * 512 + (w & 1) * 256 + lane * 4) = acc;
}

// f16 aggregate (verified)
__global__ __launch_bounds__(256)
void agg_h(const unsigned short* __restrict__ Xh, const int* __restrict__ cnt,
           const int* __restrict__ slots, unsigned short* __restrict__ Abh) {
    const int w = blockIdx.x * 4 + (threadIdx.x >> 6);
    if (w >= NSEG) return;
    const int lane = threadIdx.x & 63;
    const int m = min(cnt[w], CAP);
    const int* sl = slots + (size_t)w * CAP;
    float ac[4] = {};
    for (int i = 0; i < m; ++i) {
        const ushort4 v = *(const ushort4*)(Xh + (size_t)sl[i] * 256 + lane * 4);
        ac[0] += h2f(v.x); ac[1] += h2f(v.y); ac[2] += h2f(v.z); ac[3] += h2f(v.w);
    }
    const float inv = (m > 0) ? 1.0f / (float)m : 0.0f;
    ushort4 o = make_ushort4(f2h(ac[0] * inv), f2h(ac[1] * inv),
                             f2h(ac[2] * inv), f2h(ac[3] * inv));
    *(ushort4*)(Abh + (size_t)(w >> 1) * 512 + (w & 1) * 256 + lane * 4) = o;
}

// ===========================================================================
// Exact gate pipeline (verified R8)
// ===========================================================================
__global__ __launch_bounds__(256)
void fold1(const float* __restrict__ W_root, const float* __restrict__ W_rel,
           const float* __restrict__ b_rg, const float* __restrict__ wg,
           float* __restrict__ wfold, float* __restrict__ c3) {
    const int idx = blockIdx.x * 256 + threadIdx.x;
    if (idx < 1536) {
        const int d = idx / 6, jj = idx % 6, c = jj >> 1, j = jj & 1;
        const float* row = (c == 0) ? W_root + (size_t)d * 256
                                    : W_rel + (size_t)(c - 1) * 65536 + (size_t)d * 256;
        float s = 0.f;
        for (int e = 0; e < 256; ++e) s += row[e] * wg[e * 2 + j];
        wfold[idx] = s;
    } else if (idx < 1538) {
        const int j = idx - 1536;
        float s = 0.f;
        for (int e = 0; e < 256; ++e) s += b_rg[e] * wg[e * 2 + j];
        c3[j] = s;
    }
}

__global__ __launch_bounds__(256)
void fold2(const float* __restrict__ W_root, const float* __restrict__ W_rel,
           const float* __restrict__ b_rg, const float* __restrict__ wfold,
           float* __restrict__ W6, float* __restrict__ cb) {
    const int idx = blockIdx.x * 256 + threadIdx.x;
    if (idx < 4608) {
        const int k = idx / 6, j = idx % 6;
        const float* row = (k < 256) ? W_root + (size_t)k * 256
                                     : W_rel + (size_t)(k - 256) * 256;
        float s = 0.f;
        for (int d = 0; d < 256; ++d) s += row[d] * wfold[d * 6 + j];
        W6[idx] = s;
    } else if (idx < 4614) {
        const int j = idx - 4608;
        float s = 0.f;
        for (int d = 0; d < 256; ++d) s += b_rg[d] * wfold[d * 6 + j];
        cb[j] = s;
    }
}

__global__ __launch_bounds__(256)
void vu_kernel(const float* __restrict__ X1, const float* __restrict__ Ab,
               const float* __restrict__ W6, float* __restrict__ VU, int M) {
    __shared__ float wl[768 * 6];
    for (int i = threadIdx.x; i < 768 * 6; i += 256) wl[i] = W6[i];
    __syncthreads();
    const int wave = threadIdx.x >> 6, lane = threadIdx.x & 63;
    const int n = blockIdx.x * 4 + wave;
    if (n >= M) return;
    const float4 xv = ((const float4*)(X1 + (size_t)n * 256))[lane];
    const float4 a0 = ((const float4*)(Ab + (size_t)n * 512))[lane];
    const float4 a1 = ((const float4*)(Ab + (size_t)n * 512))[lane + 64];
    const float xa[12] = {xv.x, xv.y, xv.z, xv.w, a0.x, a0.y, a0.z, a0.w,
                          a1.x, a1.y, a1.z, a1.w};
    float z[6] = {};
    #pragma unroll
    for (int t = 0; t < 3; ++t)
        #pragma unroll
        for (int i = 0; i < 4; ++i) {
            const int k = t * 256 + lane * 4 + i;
            #pragma unroll
            for (int j = 0; j < 6; ++j) z[j] = fmaf(xa[t * 4 + i], wl[k * 6 + j], z[j]);
        }
    #pragma unroll
    for (int off = 32; off; off >>= 1)
        #pragma unroll
        for (int j = 0; j < 6; ++j) z[j] += __shfl_down(z[j], off, 64);
    if (lane == 0) {
        #pragma unroll
        for (int j = 0; j < 6; ++j) VU[(size_t)n * 6 + j] = z[j];
    }
}

__global__ __launch_bounds__(256)
void u_gate(const float* __restrict__ VU, const int* __restrict__ cnt,
            const int* __restrict__ slots, const float* __restrict__ cb,
            const float* __restrict__ c3, int* __restrict__ sel, int M) {
    const int n = blockIdx.x * 256 + threadIdx.x;
    if (n >= M) return;
    float z0 = VU[(size_t)n * 6 + 0] + cb[0] + c3[0];
    float z1 = VU[(size_t)n * 6 + 1] + cb[1] + c3[1];
    #pragma unroll
    for (int r = 0; r < 2; ++r) {
        const int seg = n * 2 + r;
        const int m = min(cnt[seg], CAP);
        if (m > 0) {
            const int* sl = slots + (size_t)seg * CAP;
            float s0 = 0.f, s1 = 0.f;
            for (int i = 0; i < m; ++i) {
                const int src = sl[i];
                s0 += VU[(size_t)src * 6 + 2 + 2 * r];
                s1 += VU[(size_t)src * 6 + 3 + 2 * r];
            }
            const float inv = 1.0f / (float)m;
            z0 += s0 * inv + cb[2 + 2 * r];
            z1 += s1 * inv + cb[3 + 2 * r];
        }
    }
    sel[n] = (z1 > z0) ? 1 : 0;
}

// expert permutation: expert0 list grows from 0, expert1 from N_NODES down
__global__ __launch_bounds__(256)
void build_perm(const int* __restrict__ sel, int* __restrict__ perm, int* c01) {
    const int n = blockIdx.x * 256 + threadIdx.x;
    if (n >= N_NODES) return;
    if (sel[n] == 0) perm[atomicAdd(&c01[0], 1)] = n;
    else             perm[N_NODES - 1 - atomicAdd(&c01[1], 1)] = n;
}

// ===========================================================================
// weight prep
// ===========================================================================
// f16x2 planes for W_in (transposed): plane0 h1, plane1 (w-h1)*2048
__global__ __launch_bounds__(256)
void wconv2(const float* __restrict__ src, unsigned short* __restrict__ dst) {
    const int i = blockIdx.x * 256 + threadIdx.x;   // 256x256
    const int k = i >> 8, n = i & 255;
    const float v = src[i];
    const _Float16 h1 = (_Float16)v;
    const float r1 = (v - (float)h1) * 2048.0f;
    dst[(size_t)n * 256 + k] = f2h(v);
    dst[65536 + (size_t)n * 256 + k] = *(unsigned short*)&h1 == 0 ? f2h(r1) : f2h(r1);
}

struct WJH { const float* src[8]; unsigned short* dst[8]; int stride[8]; int koff[8]; };
__global__ __launch_bounds__(256)
void wconv_h(WJH j) {
    const int job = blockIdx.y;
    const int i = blockIdx.x * 256 + threadIdx.x;
    const int k = i >> 8, n = i & 255;
    j.dst[job][(size_t)n * j.stride[job] + j.koff[job] + k] = f2h(j.src[job][i]);
}

// ===========================================================================
extern "C" void kernel_launch(void* const* d_in, const int* in_sizes, int n_in,
                              void* d_out, int out_size, void* d_ws, size_t ws_size,
                              hipStream_t stream) {
    const float* des    = (const float*)d_in[0];
    const float* twt    = (const float*)d_in[1];
    const float* nump   = (const float*)d_in[2];
    const float* catp   = (const float*)d_in[3];
    const int*   ei     = (const int*)d_in[4];
    const int*   et     = (const int*)d_in[5];
    const float* W_in   = (const float*)d_in[6];
    const float* b_in   = (const float*)d_in[7];
    const float* W_rel  = (const float*)d_in[8];
    const float* W_root = (const float*)d_in[9];
    const float* b_rg   = (const float*)d_in[10];
    const float* w_gate = (const float*)d_in[11];
    const float* We1    = (const float*)d_in[12];
    const float* be1    = (const float*)d_in[13];
    const float* We2    = (const float*)d_in[14];
    const float* be2    = (const float*)d_in[15];

    // ---- workspace (~196 MB) ----
    char* ws = (char*)d_ws;
    size_t off = 0;
    auto alloc = [&](size_t bytes) { char* p = ws + off; off += (bytes + 255) & ~(size_t)255; return p; };
    float* X1f  = (float*)alloc((size_t)M_PAD * 256 * 4);      // 51.25 MB
    char*  regA = alloc((size_t)M_PAD * 512 * 4);              // 102.5 MB: Ab1f | Ab2h , H
    unsigned short* X2h = (unsigned short*)alloc((size_t)M_PAD * 256 * 2);  // 25.6 MB
    float* VU   = (float*)alloc((size_t)N_NODES * 6 * 4);
    int*   cnt  = (int*)alloc((size_t)NSEG * 4);
    int*   sel  = (int*)alloc((size_t)N_NODES * 4);
    int*   perm = (int*)alloc((size_t)N_NODES * 4);
    int*   c01  = (int*)alloc(256);
    int*   slots= (int*)alloc((size_t)NSEG * CAP * 4);         // 12.8 MB
    unsigned short* wt_in2 = (unsigned short*)alloc((size_t)2 * 65536 * 2);
    unsigned short* wt_rg  = (unsigned short*)alloc((size_t)256 * 768 * 2);
    unsigned short* wt_e1  = (unsigned short*)alloc((size_t)2 * 65536 * 2);
    unsigned short* wt_e2  = (unsigned short*)alloc((size_t)2 * 65536 * 2);
    float* wfold = (float*)alloc(256 * 6 * 4);
    float* c3    = (float*)alloc(8);
    float* W6    = (float*)alloc(768 * 6 * 4);
    float* cb    = (float*)alloc(24);

    float* Ab1f = (float*)regA;                                   // fp32, layer-1
    unsigned short* Ab2h = (unsigned short*)regA;                 // f16, layer-2 (Ab1f dead)
    unsigned short* H    = (unsigned short*)(regA + (size_t)M_PAD * 512 * 2); // f16 [n][256]
    unsigned short* X3h  = (unsigned short*)X1f;                  // f16, after X1f dead

    const dim3 blk(256);

    // ---- prep ----
    hipMemsetAsync(cnt, 0, (size_t)NSEG * 4, stream);
    hipMemsetAsync(c01, 0, 8, stream);
    csr_build<<<(N_EDGES + 255) / 256, blk, 0, stream>>>(ei, et, cnt, slots);
    wconv2<<<256, blk, 0, stream>>>(W_in, wt_in2);
    {
        WJH j{};
        j.src[0] = W_root;         j.dst[0] = wt_rg;         j.stride[0] = 768; j.koff[0] = 0;
        j.src[1] = W_rel;          j.dst[1] = wt_rg;         j.stride[1] = 768; j.koff[1] = 256;
        j.src[2] = W_rel + 65536;  j.dst[2] = wt_rg;         j.stride[2] = 768; j.koff[2] = 512;
        j.src[3] = We1;            j.dst[3] = wt_e1;         j.stride[3] = 256; j.koff[3] = 0;
        j.src[4] = We1 + 65536;    j.dst[4] = wt_e1 + 65536; j.stride[4] = 256; j.koff[4] = 0;
        j.src[5] = We2;            j.dst[5] = wt_e2;         j.stride[5] = 256; j.koff[5] = 0;
        j.src[6] = We2 + 65536;    j.dst[6] = wt_e2 + 65536; j.stride[6] = 256; j.koff[6] = 0;
        wconv_h<<<dim3(256, 7), blk, 0, stream>>>(j);
    }
    fold1<<<7, blk, 0, stream>>>(W_root, W_rel, b_rg, w_gate, wfold, c3);
    fold2<<<19, blk, 0, stream>>>(W_root, W_rel, b_rg, wfold, W6, cb);

    // ---- stage 1: X1f = selu(concat @ W_in + b_in)  [f16x2, fp32-grade] ----
    {
        SArgs g{};
        g.sl[0] = {des,  128, 0,   N_NODES};
        g.sl[1] = {twt,  64,  128, N_NODES};
        g.sl[2] = {nump, 32,  192, N_NODES};
        g.sl[3] = {catp, 32,  224, N_NODES};
        g.nslab = 4; g.wt = wt_in2; g.Ktot = 256; g.M = N_NODES;
        g.bias = b_in; g.out = X1f;
        hipLaunchKernelGGL((sgemm<1>), dim3(391, 2), blk, 0, stream, g);
    }

    // ---- layer-1 aggregate (fp32, full M) ----
    aggregate<<<(NSEG + 3) / 4, blk, 0, stream>>>(X1f, cnt, slots, Ab1f, 0, NSEG);

    // ---- exact gate pipeline (fp32) ----
    vu_kernel<<<(N_NODES + 3) / 4, blk, 0, stream>>>(X1f, Ab1f, W6, VU, N_NODES);
    u_gate<<<(N_NODES + 255) / 256, blk, 0, stream>>>(VU, cnt, slots, cb, c3, sel, N_NODES);
    build_perm<<<(N_NODES + 255) / 256, blk, 0, stream>>>(sel, perm, c01);

    // ---- layer 1: X2h = [X1f|Ab1f] @ W_all + b   (f16 MFMA, fp32-cvt A) ----
    {
        HArgs g{};
        g.sl[0] = {X1f,        256, 0};
        g.sl[1] = {Ab1f,       512, 256};
        g.sl[2] = {Ab1f + 256, 512, 512};
        g.nslab = 3; g.wt = wt_rg; g.Ktot = 768; g.M = N_NODES;
        g.bias = b_rg; g.out = X2h; g.ldc = 256;
        hipLaunchKernelGGL((hgemm<0, false, false, true, true, false, false>),
                           dim3(391, 2), blk, 0, stream, g);
    }

    // ---- layer-2 aggregate (f16) ----
    agg_h<<<(NSEG + 3) / 4, blk, 0, stream>>>(X2h, cnt, slots, Ab2h);

    // ---- layer 2: X3h = [X2h|Ab2h] @ W_all + b   (f16 direct) ----
    {
        HArgs g{};
        g.sl[0] = {X2h,        256, 0};
        g.sl[1] = {Ab2h,       512, 256};
        g.sl[2] = {Ab2h + 256, 512, 512};
        g.nslab = 3; g.wt = wt_rg; g.Ktot = 768; g.M = N_NODES;
        g.bias = b_rg; g.out = X3h; g.ldc = 256;
        hipLaunchKernelGGL((hgemm<0, false, false, true, false, false, false>),
                           dim3(391, 2), blk, 0, stream, g);
    }

    // ---- MoE h1, selected expert only (permuted gather/scatter) ----
    {
        HArgs g{};
        g.sl[0] = {X3h, 256, 0};
        g.nslab = 1; g.wt = wt_e1; g.Ktot = 256; g.M = N_NODES;
        g.bias = be1; g.perm = perm; g.c01 = c01; g.out = H; g.ldc = 256;
        hipLaunchKernelGGL((hgemm<2, false, false, true, false, true, true>),
                           dim3(391, 2, 2), blk, 0, stream, g);
    }

    // ---- MoE out: d_out[n] = H[n] @ We2[sel[n]] + be2[sel[n]]  (permuted) ----
    {
        HArgs g{};
        g.sl[0] = {H, 256, 0};
        g.nslab = 1; g.wt = wt_e2; g.Ktot = 256; g.M = N_NODES;
        g.bias = be2; g.perm = perm; g.c01 = c01; g.out = d_out; g.ldc = 256;
        hipLaunchKernelGGL((hgemm<0, false, false, false, false, true, true>),
                           dim3(391, 2, 2), blk, 0, stream, g);
    }
}